// Round 1
// 301.780 us; speedup vs baseline: 1.0128x; 1.0128x over previous
//
#include <hip/hip_runtime.h>
#include <hip/hip_fp8.h>
#include <math.h>

typedef __attribute__((ext_vector_type(2))) float fv2;

#if defined(__has_builtin)
#  if __has_builtin(__builtin_amdgcn_cvt_pk_f32_fp8) && \
      __has_builtin(__builtin_amdgcn_cvt_pk_fp8_f32)
#    define PE_HAVE_FP8_BUILTINS 1
#  endif
#endif

// pack 4 floats -> 4 fp8 e4m3 bytes in one uint32
__device__ __forceinline__ unsigned pack4_fp8(float a, float b, float c, float d) {
#ifdef PE_HAVE_FP8_BUILTINS
    int w = 0;
    w = __builtin_amdgcn_cvt_pk_fp8_f32(a, b, w, false);  // bytes 0,1
    w = __builtin_amdgcn_cvt_pk_fp8_f32(c, d, w, true);   // bytes 2,3
    return (unsigned)w;
#else
    unsigned r = 0;
    r |= (unsigned)__hip_fp8_e4m3(a).__x;
    r |= (unsigned)__hip_fp8_e4m3(b).__x << 8;
    r |= (unsigned)__hip_fp8_e4m3(c).__x << 16;
    r |= (unsigned)__hip_fp8_e4m3(d).__x << 24;
    return r;
#endif
}

// fp32 dot of two uint32s each holding 4 fp8 e4m3 values
__device__ __forceinline__ float dot4w_fp8(unsigned qa, unsigned ka, float acc) {
#ifdef PE_HAVE_FP8_BUILTINS
    fv2 q0 = __builtin_amdgcn_cvt_pk_f32_fp8((int)qa, false);
    fv2 q1 = __builtin_amdgcn_cvt_pk_f32_fp8((int)qa, true);
    fv2 k0 = __builtin_amdgcn_cvt_pk_f32_fp8((int)ka, false);
    fv2 k1 = __builtin_amdgcn_cvt_pk_f32_fp8((int)ka, true);
    acc = fmaf(q0.x, k0.x, acc);
    acc = fmaf(q0.y, k0.y, acc);
    acc = fmaf(q1.x, k1.x, acc);
    acc = fmaf(q1.y, k1.y, acc);
    return acc;
#else
#pragma unroll
    for (int j = 0; j < 4; ++j) {
        __hip_fp8_e4m3 qv, kv;
        qv.__x = (qa >> (8 * j)) & 0xff;
        kv.__x = (ka >> (8 * j)) & 0xff;
        acc = fmaf((float)qv, (float)kv, acc);
    }
    return acc;
#endif
}

// 16-byte (quarter-row) fp8 dot
__device__ __forceinline__ float dot16_fp8(const uint4& q, const uint4& k) {
    float d = 0.0f;
    d = dot4w_fp8(q.x, k.x, d);
    d = dot4w_fp8(q.y, k.y, d);
    d = dot4w_fp8(q.z, k.z, d);
    d = dot4w_fp8(q.w, k.w, d);
    return d;
}

__device__ __forceinline__ float red4(float d) {
    d += __shfl_xor(d, 1, 64);
    d += __shfl_xor(d, 2, 64);
    return d;
}

// Hardware fp32 atomic add (global_atomic_add_f32, memory-side, fire-and-forget).
// Plain atomicAdd(float*) lowers to a CAS retry loop without -munsafe-fp-atomics,
// which under 524k concurrent edge-writers causes cross-XCD cacheline ping-pong
// and multi-thousand-cycle retry round trips (the 174us / 9% VALUBusy pathology).
// No intra-kernel reader of the destination exists, so no "memory" clobber is
// needed (keeps the compiler free to hoist the next iteration's loads past it).
__device__ __forceinline__ void atomic_add_f32_hw(float* p, float v) {
    asm volatile("global_atomic_add_f32 %0, %1, off" : : "v"(p), "v"(v));
}

// Pass 0: fp32 -> fp8 e4m3; also zeroes node_sum and out (fused memsets).
// Thread i converts 4 consecutive floats (one float4 -> one packed uint):
// 16 B/lane coalesced loads, contiguous 4 B/lane stores. (The previous
// 16-floats/thread version had each load instruction touching 64 distinct
// cache lines at 16B-of-64B utilization.)
__global__ __launch_bounds__(256) void pe_convert_kernel(
    const float* __restrict__ Q,
    const float* __restrict__ K,
    unsigned* __restrict__ Qq,   // row = 16 uints = 64 fp8
    unsigned* __restrict__ Kq,
    float* __restrict__ node_sum,
    float* __restrict__ out,
    int n4,           // total elements / 4
    int num_nodes,
    int num_graphs) {
    const int i = blockIdx.x * blockDim.x + threadIdx.x;
    if (i < num_nodes) node_sum[i] = 0.0f;
    if (i < num_graphs) out[i] = 0.0f;
    if (i >= n4) return;

    const float4 q = ((const float4*)Q)[i];
    const float4 k = ((const float4*)K)[i];
    Qq[i] = pack4_fp8(q.x, q.y, q.z, q.w);
    Kq[i] = pack4_fp8(k.x, k.y, k.z, k.w);
}

// Pass 1: 4 lanes per edge (row = 64 fp8 = 64 B = exactly ONE cache line;
// lane sub reads uint4 #sub). 4 edges per group-iteration: 8 gather loads
// issued per iter, and after the 2-step butterfly every lane of the group
// holds all 4 dots -> each of the 4 lanes fires one edge's atomic, so ALL 64
// lanes of the wave participate in a single atomic instruction (64 edges).
__global__ __launch_bounds__(256) void pe_edge_kernel(
    const unsigned* __restrict__ Qq,
    const unsigned* __restrict__ Kq,
    const int* __restrict__ c,
    const int* __restrict__ u,
    float* __restrict__ node_sum,
    int num_edges) {
    const int tid = blockIdx.x * blockDim.x + threadIdx.x;
    const int group = tid >> 2;
    const int sub = tid & 3;
    const int ngroups = (gridDim.x * blockDim.x) >> 2;
    const float inv_scale = 0.125f;  // 1/sqrt(64)

    const int E4 = num_edges & ~3;

    for (int base = group * 4; base < E4; base += ngroups * 4) {
        const int4 ci = *(const int4*)(c + base);
        const int4 ui = *(const int4*)(u + base);

        const uint4 q0 = *(const uint4*)(Qq + (size_t)ci.x * 16 + sub * 4);
        const uint4 q1 = *(const uint4*)(Qq + (size_t)ci.y * 16 + sub * 4);
        const uint4 q2 = *(const uint4*)(Qq + (size_t)ci.z * 16 + sub * 4);
        const uint4 q3 = *(const uint4*)(Qq + (size_t)ci.w * 16 + sub * 4);
        const uint4 k0 = *(const uint4*)(Kq + (size_t)ui.x * 16 + sub * 4);
        const uint4 k1 = *(const uint4*)(Kq + (size_t)ui.y * 16 + sub * 4);
        const uint4 k2 = *(const uint4*)(Kq + (size_t)ui.z * 16 + sub * 4);
        const uint4 k3 = *(const uint4*)(Kq + (size_t)ui.w * 16 + sub * 4);

        float d0 = red4(dot16_fp8(q0, k0));
        float d1 = red4(dot16_fp8(q1, k1));
        float d2 = red4(dot16_fp8(q2, k2));
        float d3 = red4(dot16_fp8(q3, k3));

        const float dsel = (sub == 0) ? d0 : (sub == 1) ? d1 : (sub == 2) ? d2 : d3;
        const int csel = (sub == 0) ? ci.x : (sub == 1) ? ci.y : (sub == 2) ? ci.z : ci.w;
        atomic_add_f32_hw(&node_sum[csel], __expf(dsel * inv_scale));
    }

    // tail (num_edges % 4): one edge per group
    for (int e = E4 + group; e < num_edges; e += ngroups) {
        const int cc = c[e];
        const int uu = u[e];
        const uint4 q = *(const uint4*)(Qq + (size_t)cc * 16 + sub * 4);
        const uint4 k = *(const uint4*)(Kq + (size_t)uu * 16 + sub * 4);
        float d = red4(dot16_fp8(q, k));
        if (sub == 0) atomic_add_f32_hw(&node_sum[cc], __expf(d * inv_scale));
    }
}

// Pass 2: lse = log(node_sum[n]) (0 for empty), segment-sum into out[batch[n]].
__global__ __launch_bounds__(256) void pe_node_kernel(
    const float* __restrict__ node_sum,
    const int* __restrict__ batch,
    float* __restrict__ out,
    int num_nodes) {
    const int n = blockIdx.x * blockDim.x + threadIdx.x;
    const bool valid = (n < num_nodes);
    const int nc = valid ? n : (num_nodes - 1);

    const float s = valid ? node_sum[nc] : 0.0f;
    float lse = (s > 0.0f) ? logf(s) : 0.0f;
    if (!valid) lse = 0.0f;
    const int b = batch[nc];

    const int b0 = __shfl(b, 0, 64);
    const bool uniform = __all(b == b0);
    if (uniform) {
        lse += __shfl_xor(lse, 1, 64);
        lse += __shfl_xor(lse, 2, 64);
        lse += __shfl_xor(lse, 4, 64);
        lse += __shfl_xor(lse, 8, 64);
        lse += __shfl_xor(lse, 16, 64);
        lse += __shfl_xor(lse, 32, 64);
        if ((threadIdx.x & 63) == 0 && lse != 0.0f) {
            atomic_add_f32_hw(&out[b0], lse);
        }
    } else {
        if (valid && lse != 0.0f) {
            atomic_add_f32_hw(&out[b], lse);
        }
    }
}

extern "C" void kernel_launch(void* const* d_in, const int* in_sizes, int n_in,
                              void* d_out, int out_size, void* d_ws, size_t ws_size,
                              hipStream_t stream) {
    const float* Q2 = (const float*)d_in[0];
    const float* K2 = (const float*)d_in[1];
    const int* c_2 = (const int*)d_in[2];
    const int* u_2 = (const int*)d_in[3];
    const int* batch = (const int*)d_in[4];

    const int num_nodes = in_sizes[4];
    const int num_edges = in_sizes[2];
    const int num_graphs = out_size;
    const int d = in_sizes[0] / num_nodes;   // 64
    const size_t row_elems = (size_t)num_nodes * d;

    // d_ws layout: Qq (row_elems fp8) | Kq (row_elems fp8) | node_sum (fp32)
    unsigned* Qq = (unsigned*)d_ws;
    unsigned* Kq = Qq + row_elems / 4;       // row_elems bytes
    float* node_sum = (float*)(Kq + row_elems / 4);
    float* out = (float*)d_out;

    // Pass 0: fp32 -> fp8 + fused zeroing of node_sum/out
    {
        const int n4 = (int)(row_elems / 4);
        const int block = 256;
        const int grid = (n4 + block - 1) / block;   // covers num_nodes too
        pe_convert_kernel<<<grid, block, 0, stream>>>(Q2, K2, Qq, Kq,
                                                      node_sum, out,
                                                      n4, num_nodes, num_graphs);
    }

    // Pass 1: edge gather + exp + node atomic (4 lanes/edge, 4 edges/iter)
    {
        const int block = 256;
        const int grid = 8192;
        pe_edge_kernel<<<grid, block, 0, stream>>>(Qq, Kq, c_2, u_2,
                                                   node_sum, num_edges);
    }

    // Pass 2: log + per-graph sum
    {
        const int block = 256;
        const int grid = (num_nodes + block - 1) / block;
        pe_node_kernel<<<grid, block, 0, stream>>>(node_sum, batch, out,
                                                   num_nodes);
    }
}

// Round 2
// 282.216 us; speedup vs baseline: 1.0830x; 1.0693x over previous
//
#include <hip/hip_runtime.h>
#include <hip/hip_fp8.h>
#include <math.h>

typedef __attribute__((ext_vector_type(2))) float fv2;

#if defined(__has_builtin)
#  if __has_builtin(__builtin_amdgcn_cvt_pk_f32_fp8) && \
      __has_builtin(__builtin_amdgcn_cvt_pk_fp8_f32)
#    define PE_HAVE_FP8_BUILTINS 1
#  endif
#endif

#define MAX_NB 1024          // max buckets supported by binned path
#define NPB 256              // nodes per bucket
#define NPB_SHIFT 8
#define E1_EPT 16            // edges per thread in bin kernel
#define E1_CHUNK (E1_EPT * 256)

// pack 4 floats -> 4 fp8 e4m3 bytes in one uint32
__device__ __forceinline__ unsigned pack4_fp8(float a, float b, float c, float d) {
#ifdef PE_HAVE_FP8_BUILTINS
    int w = 0;
    w = __builtin_amdgcn_cvt_pk_fp8_f32(a, b, w, false);  // bytes 0,1
    w = __builtin_amdgcn_cvt_pk_fp8_f32(c, d, w, true);   // bytes 2,3
    return (unsigned)w;
#else
    unsigned r = 0;
    r |= (unsigned)__hip_fp8_e4m3(a).__x;
    r |= (unsigned)__hip_fp8_e4m3(b).__x << 8;
    r |= (unsigned)__hip_fp8_e4m3(c).__x << 16;
    r |= (unsigned)__hip_fp8_e4m3(d).__x << 24;
    return r;
#endif
}

__device__ __forceinline__ float dot4w_fp8(unsigned qa, unsigned ka, float acc) {
#ifdef PE_HAVE_FP8_BUILTINS
    fv2 q0 = __builtin_amdgcn_cvt_pk_f32_fp8((int)qa, false);
    fv2 q1 = __builtin_amdgcn_cvt_pk_f32_fp8((int)qa, true);
    fv2 k0 = __builtin_amdgcn_cvt_pk_f32_fp8((int)ka, false);
    fv2 k1 = __builtin_amdgcn_cvt_pk_f32_fp8((int)ka, true);
    acc = fmaf(q0.x, k0.x, acc);
    acc = fmaf(q0.y, k0.y, acc);
    acc = fmaf(q1.x, k1.x, acc);
    acc = fmaf(q1.y, k1.y, acc);
    return acc;
#else
#pragma unroll
    for (int j = 0; j < 4; ++j) {
        __hip_fp8_e4m3 qv, kv;
        qv.__x = (qa >> (8 * j)) & 0xff;
        kv.__x = (ka >> (8 * j)) & 0xff;
        acc = fmaf((float)qv, (float)kv, acc);
    }
    return acc;
#endif
}

__device__ __forceinline__ float dot16_fp8(const uint4& q, const uint4& k) {
    float d = 0.0f;
    d = dot4w_fp8(q.x, k.x, d);
    d = dot4w_fp8(q.y, k.y, d);
    d = dot4w_fp8(q.z, k.z, d);
    d = dot4w_fp8(q.w, k.w, d);
    return d;
}

__device__ __forceinline__ float red4(float d) {
    d += __shfl_xor(d, 1, 64);
    d += __shfl_xor(d, 2, 64);
    return d;
}

// Pass 0: fp32 -> fp8 e4m3 rows; fused zeroing of out, bucket counters
// (binned path) or node_sum (fallback path).
__global__ __launch_bounds__(256) void pe_convert_kernel(
    const float* __restrict__ Q,
    const float* __restrict__ K,
    unsigned* __restrict__ Qq,   // row = 16 uints = 64 fp8
    unsigned* __restrict__ Kq,
    float* __restrict__ node_sum,     // may be null (binned path)
    unsigned* __restrict__ bucket_cnt,// may be null (fallback path)
    float* __restrict__ out,
    int n4,           // total elements / 4
    int num_nodes,
    int num_graphs) {
    const int i = blockIdx.x * blockDim.x + threadIdx.x;
    if (node_sum && i < num_nodes) node_sum[i] = 0.0f;
    if (bucket_cnt && i < MAX_NB) bucket_cnt[i] = 0u;
    if (i < num_graphs) out[i] = 0.0f;
    if (i >= n4) return;

    const float4 q = ((const float4*)Q)[i];
    const float4 k = ((const float4*)K)[i];
    Qq[i] = pack4_fp8(q.x, q.y, q.z, q.w);
    Kq[i] = pack4_fp8(k.x, k.y, k.z, k.w);
}

// Histogram of edge destinations by bucket (c >> NPB_SHIFT).
__global__ __launch_bounds__(256) void pe_hist_kernel(
    const int* __restrict__ c,
    unsigned* __restrict__ bucket_cnt,
    int num_edges, int nb) {
    __shared__ unsigned h[MAX_NB];
    const int tid = threadIdx.x;
    for (int b = tid; b < nb; b += 256) h[b] = 0u;
    __syncthreads();

    const int stride = gridDim.x * blockDim.x;
    const int gid = blockIdx.x * blockDim.x + tid;
    const int E4 = num_edges >> 2;
    for (int k = gid; k < E4; k += stride) {
        const int4 v = ((const int4*)c)[k];
        atomicAdd(&h[v.x >> NPB_SHIFT], 1u);
        atomicAdd(&h[v.y >> NPB_SHIFT], 1u);
        atomicAdd(&h[v.z >> NPB_SHIFT], 1u);
        atomicAdd(&h[v.w >> NPB_SHIFT], 1u);
    }
    for (int e = (E4 << 2) + gid; e < num_edges; e += stride)
        atomicAdd(&h[c[e] >> NPB_SHIFT], 1u);
    __syncthreads();

    for (int b = tid; b < nb; b += 256)
        if (h[b]) atomicAdd(&bucket_cnt[b], h[b]);
}

// Exclusive scan of bucket_cnt -> bucket_base[0..nb], gcursor = base.
// Single block of 1024 threads, Hillis-Steele in LDS.
__global__ __launch_bounds__(1024) void pe_scan_kernel(
    const unsigned* __restrict__ bucket_cnt,
    unsigned* __restrict__ bucket_base,
    unsigned* __restrict__ gcursor,
    int nb) {
    __shared__ unsigned s[MAX_NB];
    const int t = threadIdx.x;
    const unsigned v = (t < nb) ? bucket_cnt[t] : 0u;
    s[t] = v;
    __syncthreads();
    for (int off = 1; off < MAX_NB; off <<= 1) {
        const unsigned mine = s[t];
        const unsigned add = (t >= off) ? s[t - off] : 0u;
        __syncthreads();
        s[t] = mine + add;
        __syncthreads();
    }
    const unsigned excl = s[t] - v;
    if (t < nb) {
        bucket_base[t] = excl;
        gcursor[t] = excl;
    }
    if (t == 0) bucket_base[nb] = s[MAX_NB - 1];
}

// Bin kernel: gather + dot + exp (same 4-lane team scheme as before), then
// partition (node, exp) pairs into per-bucket runs. Per 4096-edge block:
// one LDS-counted reservation round -> ~nb returning int atomics per block
// (~306k total, 10x fewer than per-edge f32 atomics), pairs written as plain
// cacheable stores (L2 write-combines each block's ~10-pair contiguous runs).
__global__ __launch_bounds__(256) void pe_bin_kernel(
    const unsigned* __restrict__ Qq,
    const unsigned* __restrict__ Kq,
    const int* __restrict__ c,
    const int* __restrict__ u,
    unsigned* __restrict__ gcursor,
    uint2* __restrict__ pairs,
    int num_edges, int nb) {
    __shared__ unsigned cnt[MAX_NB];
    __shared__ unsigned basesh[MAX_NB];

    const int tid = threadIdx.x;
    const int g4 = (tid >> 2) * 4;  // team's 4-edge offset within the 256
    const int sub = tid & 3;
    const int estart = blockIdx.x * E1_CHUNK;
    const int eend = min(estart + E1_CHUNK, num_edges);
    const float inv_scale = 0.125f;  // 1/sqrt(64)

    for (int b = tid; b < nb; b += 256) cnt[b] = 0u;
    __syncthreads();

    int pc[E1_EPT];
    float pv[E1_EPT];
    int pr[E1_EPT];

#pragma unroll
    for (int j = 0; j < E1_EPT; ++j) {
        pc[j] = -1;
        const int base = estart + j * 256;
        if (base < eend) {          // uniform across the block
            const int tb = base + g4;
            int4 ci, ui;
            if (tb + 3 < eend) {
                ci = *(const int4*)(c + tb);
                ui = *(const int4*)(u + tb);
            } else {
                ci.x = (tb + 0 < eend) ? c[tb + 0] : 0;
                ci.y = (tb + 1 < eend) ? c[tb + 1] : 0;
                ci.z = (tb + 2 < eend) ? c[tb + 2] : 0;
                ci.w = (tb + 3 < eend) ? c[tb + 3] : 0;
                ui.x = (tb + 0 < eend) ? u[tb + 0] : 0;
                ui.y = (tb + 1 < eend) ? u[tb + 1] : 0;
                ui.z = (tb + 2 < eend) ? u[tb + 2] : 0;
                ui.w = (tb + 3 < eend) ? u[tb + 3] : 0;
            }

            const uint4 q0 = *(const uint4*)(Qq + (size_t)ci.x * 16 + sub * 4);
            const uint4 q1 = *(const uint4*)(Qq + (size_t)ci.y * 16 + sub * 4);
            const uint4 q2 = *(const uint4*)(Qq + (size_t)ci.z * 16 + sub * 4);
            const uint4 q3 = *(const uint4*)(Qq + (size_t)ci.w * 16 + sub * 4);
            const uint4 k0 = *(const uint4*)(Kq + (size_t)ui.x * 16 + sub * 4);
            const uint4 k1 = *(const uint4*)(Kq + (size_t)ui.y * 16 + sub * 4);
            const uint4 k2 = *(const uint4*)(Kq + (size_t)ui.z * 16 + sub * 4);
            const uint4 k3 = *(const uint4*)(Kq + (size_t)ui.w * 16 + sub * 4);

            const float d0 = red4(dot16_fp8(q0, k0));
            const float d1 = red4(dot16_fp8(q1, k1));
            const float d2 = red4(dot16_fp8(q2, k2));
            const float d3 = red4(dot16_fp8(q3, k3));

            const float dsel = (sub == 0) ? d0 : (sub == 1) ? d1 : (sub == 2) ? d2 : d3;
            const int csel = (sub == 0) ? ci.x : (sub == 1) ? ci.y : (sub == 2) ? ci.z : ci.w;

            // thread tid owns edge base + (tid>>2)*4 + (tid&3) == base + tid
            if (base + tid < eend) {
                pc[j] = csel;
                pv[j] = __expf(dsel * inv_scale);
                pr[j] = (int)atomicAdd(&cnt[csel >> NPB_SHIFT], 1u);
            }
        }
    }
    __syncthreads();

    for (int b = tid; b < nb; b += 256) {
        const unsigned n = cnt[b];
        basesh[b] = n ? atomicAdd(&gcursor[b], n) : 0u;
    }
    __syncthreads();

#pragma unroll
    for (int j = 0; j < E1_EPT; ++j) {
        if (pc[j] >= 0) {
            const int b = pc[j] >> NPB_SHIFT;
            pairs[basesh[b] + (unsigned)pr[j]] =
                make_uint2((unsigned)pc[j], __float_as_uint(pv[j]));
        }
    }
}

// Reduce kernel: one block per bucket. Stream the bucket's pairs, accumulate
// 256 node sums in LDS (ds_add_f32), then fused log + per-graph segment sum
// (batch sorted -> wave-uniform fast path, ~1 atomic per wave).
__global__ __launch_bounds__(256) void pe_reduce_kernel(
    const uint2* __restrict__ pairs,
    const unsigned* __restrict__ bucket_base,
    const int* __restrict__ batch,
    float* __restrict__ out,
    int num_nodes) {
    __shared__ float acc[NPB];
    const int B = blockIdx.x;
    const int t = threadIdx.x;
    acc[t] = 0.0f;
    __syncthreads();

    const unsigned s0 = bucket_base[B];
    const unsigned s1 = bucket_base[B + 1];
    for (unsigned i = s0 + t; i < s1; i += 256) {
        const uint2 p = pairs[i];
        atomicAdd(&acc[p.x & (NPB - 1)], __uint_as_float(p.y));
    }
    __syncthreads();

    const int node = (B << NPB_SHIFT) + t;
    const bool valid = node < num_nodes;
    const int nc = valid ? node : (num_nodes - 1);
    const float s = acc[t];
    float lse = (valid && s > 0.0f) ? logf(s) : 0.0f;
    const int b = batch[nc];

    const int b0 = __shfl(b, 0, 64);
    const bool uniform = __all(b == b0);
    if (uniform) {
        lse += __shfl_xor(lse, 1, 64);
        lse += __shfl_xor(lse, 2, 64);
        lse += __shfl_xor(lse, 4, 64);
        lse += __shfl_xor(lse, 8, 64);
        lse += __shfl_xor(lse, 16, 64);
        lse += __shfl_xor(lse, 32, 64);
        if ((t & 63) == 0 && lse != 0.0f) atomicAdd(&out[b0], lse);
    } else {
        if (valid && lse != 0.0f) atomicAdd(&out[b], lse);
    }
}

// ---------- fallback path (round-0 kernels, proven correct) ----------

__global__ __launch_bounds__(256) void pe_edge_kernel(
    const unsigned* __restrict__ Qq,
    const unsigned* __restrict__ Kq,
    const int* __restrict__ c,
    const int* __restrict__ u,
    float* __restrict__ node_sum,
    int num_edges) {
    const int tid = blockIdx.x * blockDim.x + threadIdx.x;
    const int group = tid >> 2;
    const int sub = tid & 3;
    const int ngroups = (gridDim.x * blockDim.x) >> 2;
    const float inv_scale = 0.125f;

    const int E4 = num_edges & ~3;

    for (int base = group * 4; base < E4; base += ngroups * 4) {
        const int4 ci = *(const int4*)(c + base);
        const int4 ui = *(const int4*)(u + base);

        const uint4 q0 = *(const uint4*)(Qq + (size_t)ci.x * 16 + sub * 4);
        const uint4 q1 = *(const uint4*)(Qq + (size_t)ci.y * 16 + sub * 4);
        const uint4 q2 = *(const uint4*)(Qq + (size_t)ci.z * 16 + sub * 4);
        const uint4 q3 = *(const uint4*)(Qq + (size_t)ci.w * 16 + sub * 4);
        const uint4 k0 = *(const uint4*)(Kq + (size_t)ui.x * 16 + sub * 4);
        const uint4 k1 = *(const uint4*)(Kq + (size_t)ui.y * 16 + sub * 4);
        const uint4 k2 = *(const uint4*)(Kq + (size_t)ui.z * 16 + sub * 4);
        const uint4 k3 = *(const uint4*)(Kq + (size_t)ui.w * 16 + sub * 4);

        float d0 = red4(dot16_fp8(q0, k0));
        float d1 = red4(dot16_fp8(q1, k1));
        float d2 = red4(dot16_fp8(q2, k2));
        float d3 = red4(dot16_fp8(q3, k3));

        const float dsel = (sub == 0) ? d0 : (sub == 1) ? d1 : (sub == 2) ? d2 : d3;
        const int csel = (sub == 0) ? ci.x : (sub == 1) ? ci.y : (sub == 2) ? ci.z : ci.w;
        atomicAdd(&node_sum[csel], __expf(dsel * inv_scale));
    }

    for (int e = E4 + group; e < num_edges; e += ngroups) {
        const int cc = c[e];
        const int uu = u[e];
        const uint4 q = *(const uint4*)(Qq + (size_t)cc * 16 + sub * 4);
        const uint4 k = *(const uint4*)(Kq + (size_t)uu * 16 + sub * 4);
        float d = red4(dot16_fp8(q, k));
        if (sub == 0) atomicAdd(&node_sum[cc], __expf(d * inv_scale));
    }
}

__global__ __launch_bounds__(256) void pe_node_kernel(
    const float* __restrict__ node_sum,
    const int* __restrict__ batch,
    float* __restrict__ out,
    int num_nodes) {
    const int n = blockIdx.x * blockDim.x + threadIdx.x;
    const bool valid = (n < num_nodes);
    const int nc = valid ? n : (num_nodes - 1);

    const float s = valid ? node_sum[nc] : 0.0f;
    float lse = (s > 0.0f) ? logf(s) : 0.0f;
    if (!valid) lse = 0.0f;
    const int b = batch[nc];

    const int b0 = __shfl(b, 0, 64);
    const bool uniform = __all(b == b0);
    if (uniform) {
        lse += __shfl_xor(lse, 1, 64);
        lse += __shfl_xor(lse, 2, 64);
        lse += __shfl_xor(lse, 4, 64);
        lse += __shfl_xor(lse, 8, 64);
        lse += __shfl_xor(lse, 16, 64);
        lse += __shfl_xor(lse, 32, 64);
        if ((threadIdx.x & 63) == 0 && lse != 0.0f) {
            atomicAdd(&out[b0], lse);
        }
    } else {
        if (valid && lse != 0.0f) {
            atomicAdd(&out[b], lse);
        }
    }
}

extern "C" void kernel_launch(void* const* d_in, const int* in_sizes, int n_in,
                              void* d_out, int out_size, void* d_ws, size_t ws_size,
                              hipStream_t stream) {
    const float* Q2 = (const float*)d_in[0];
    const float* K2 = (const float*)d_in[1];
    const int* c_2 = (const int*)d_in[2];
    const int* u_2 = (const int*)d_in[3];
    const int* batch = (const int*)d_in[4];

    const int num_nodes = in_sizes[4];
    const int num_edges = in_sizes[2];
    const int num_graphs = out_size;
    const int d = in_sizes[0] / num_nodes;   // 64
    const size_t row_elems = (size_t)num_nodes * d;
    const size_t row_bytes = row_elems;      // fp8: 1 B per element

    // ws layout: Qq | Kq | meta (bucket_cnt MAX_NB, bucket_base MAX_NB+1,
    //            gcursor MAX_NB, pad) | pairs (num_edges * 8 B)
    // fallback:  Qq | Kq | node_sum (num_nodes fp32)
    unsigned* Qq = (unsigned*)d_ws;
    unsigned* Kq = Qq + row_bytes / 4;
    unsigned* meta = Kq + row_bytes / 4;
    unsigned* bucket_cnt = meta;
    unsigned* bucket_base = meta + MAX_NB;
    unsigned* gcursor = bucket_base + MAX_NB + 1;
    uint2* pairs = (uint2*)(meta + 3 * MAX_NB + 16);
    float* node_sum = (float*)meta;
    float* out = (float*)d_out;

    const int nb = (num_nodes + NPB - 1) >> NPB_SHIFT;
    const size_t need_binned = row_bytes * 2 + (size_t)(3 * MAX_NB + 16) * 4 +
                               (size_t)num_edges * 8;
    const bool use_binned = (nb <= MAX_NB) && (ws_size >= need_binned) &&
                            (d == 64);

    // Pass 0: fp32 -> fp8 + fused zeroing
    {
        const int n4 = (int)(row_elems / 4);
        const int block = 256;
        const int grid = (n4 + block - 1) / block;
        pe_convert_kernel<<<grid, block, 0, stream>>>(
            Q2, K2, Qq, Kq,
            use_binned ? nullptr : node_sum,
            use_binned ? bucket_cnt : nullptr,
            out, n4, num_nodes, num_graphs);
    }

    if (use_binned) {
        // bucket histogram
        pe_hist_kernel<<<256, 256, 0, stream>>>(c_2, bucket_cnt, num_edges, nb);
        // exclusive scan -> bases + cursors
        pe_scan_kernel<<<1, 1024, 0, stream>>>(bucket_cnt, bucket_base, gcursor, nb);
        // gather + dot + exp + partition
        {
            const int grid = (num_edges + E1_CHUNK - 1) / E1_CHUNK;
            pe_bin_kernel<<<grid, 256, 0, stream>>>(Qq, Kq, c_2, u_2,
                                                    gcursor, pairs,
                                                    num_edges, nb);
        }
        // per-bucket LDS reduce + fused log + per-graph sum
        pe_reduce_kernel<<<nb, 256, 0, stream>>>(pairs, bucket_base, batch,
                                                 out, num_nodes);
    } else {
        {
            const int block = 256;
            const int grid = 8192;
            pe_edge_kernel<<<grid, block, 0, stream>>>(Qq, Kq, c_2, u_2,
                                                       node_sum, num_edges);
        }
        {
            const int block = 256;
            const int grid = (num_nodes + block - 1) / block;
            pe_node_kernel<<<grid, block, 0, stream>>>(node_sum, batch, out,
                                                       num_nodes);
        }
    }
}

// Round 3
// 276.859 us; speedup vs baseline: 1.1040x; 1.0193x over previous
//
#include <hip/hip_runtime.h>
#include <hip/hip_fp8.h>
#include <hip/hip_fp16.h>
#include <math.h>

typedef __attribute__((ext_vector_type(2))) float fv2;

#if defined(__has_builtin)
#  if __has_builtin(__builtin_amdgcn_cvt_pk_f32_fp8) && \
      __has_builtin(__builtin_amdgcn_cvt_pk_fp8_f32)
#    define PE_HAVE_FP8_BUILTINS 1
#  endif
#endif

#define MAX_NB 1024          // max buckets supported by binned path
#define NPB 256              // nodes per bucket
#define NPB_SHIFT 8
#define E1_EPT 8             // edges per thread in bin kernel
#define E1_CHUNK (E1_EPT * 256)   // 2048 edges per block

// pack 4 floats -> 4 fp8 e4m3 bytes in one uint32
__device__ __forceinline__ unsigned pack4_fp8(float a, float b, float c, float d) {
#ifdef PE_HAVE_FP8_BUILTINS
    int w = 0;
    w = __builtin_amdgcn_cvt_pk_fp8_f32(a, b, w, false);  // bytes 0,1
    w = __builtin_amdgcn_cvt_pk_fp8_f32(c, d, w, true);   // bytes 2,3
    return (unsigned)w;
#else
    unsigned r = 0;
    r |= (unsigned)__hip_fp8_e4m3(a).__x;
    r |= (unsigned)__hip_fp8_e4m3(b).__x << 8;
    r |= (unsigned)__hip_fp8_e4m3(c).__x << 16;
    r |= (unsigned)__hip_fp8_e4m3(d).__x << 24;
    return r;
#endif
}

__device__ __forceinline__ float dot4w_fp8(unsigned qa, unsigned ka, float acc) {
#ifdef PE_HAVE_FP8_BUILTINS
    fv2 q0 = __builtin_amdgcn_cvt_pk_f32_fp8((int)qa, false);
    fv2 q1 = __builtin_amdgcn_cvt_pk_f32_fp8((int)qa, true);
    fv2 k0 = __builtin_amdgcn_cvt_pk_f32_fp8((int)ka, false);
    fv2 k1 = __builtin_amdgcn_cvt_pk_f32_fp8((int)ka, true);
    acc = fmaf(q0.x, k0.x, acc);
    acc = fmaf(q0.y, k0.y, acc);
    acc = fmaf(q1.x, k1.x, acc);
    acc = fmaf(q1.y, k1.y, acc);
    return acc;
#else
#pragma unroll
    for (int j = 0; j < 4; ++j) {
        __hip_fp8_e4m3 qv, kv;
        qv.__x = (qa >> (8 * j)) & 0xff;
        kv.__x = (ka >> (8 * j)) & 0xff;
        acc = fmaf((float)qv, (float)kv, acc);
    }
    return acc;
#endif
}

__device__ __forceinline__ float dot16_fp8(const uint4& q, const uint4& k) {
    float d = 0.0f;
    d = dot4w_fp8(q.x, k.x, d);
    d = dot4w_fp8(q.y, k.y, d);
    d = dot4w_fp8(q.z, k.z, d);
    d = dot4w_fp8(q.w, k.w, d);
    return d;
}

__device__ __forceinline__ float red4(float d) {
    d += __shfl_xor(d, 1, 64);
    d += __shfl_xor(d, 2, 64);
    return d;
}

__device__ __forceinline__ unsigned f32_to_f16bits(float v) {
    __half h = __float2half(v);
    return (unsigned)__half_as_ushort(h);
}

__device__ __forceinline__ float f16bits_to_f32(unsigned b) {
    return __half2float(__ushort_as_half((unsigned short)(b & 0xffffu)));
}

// Pass 0: fp32 -> fp8 e4m3 rows; fused zeroing of out, bucket counters
// (binned path) or node_sum (fallback path).
__global__ __launch_bounds__(256) void pe_convert_kernel(
    const float* __restrict__ Q,
    const float* __restrict__ K,
    unsigned* __restrict__ Qq,   // row = 16 uints = 64 fp8
    unsigned* __restrict__ Kq,
    float* __restrict__ node_sum,     // may be null (binned path)
    unsigned* __restrict__ bucket_cnt,// may be null (fallback path)
    float* __restrict__ out,
    int n4,           // total elements / 4
    int num_nodes,
    int num_graphs) {
    const int i = blockIdx.x * blockDim.x + threadIdx.x;
    if (node_sum && i < num_nodes) node_sum[i] = 0.0f;
    if (bucket_cnt && i < MAX_NB) bucket_cnt[i] = 0u;
    if (i < num_graphs) out[i] = 0.0f;
    if (i >= n4) return;

    const float4 q = ((const float4*)Q)[i];
    const float4 k = ((const float4*)K)[i];
    Qq[i] = pack4_fp8(q.x, q.y, q.z, q.w);
    Kq[i] = pack4_fp8(k.x, k.y, k.z, k.w);
}

// Histogram of edge destinations by bucket (c >> NPB_SHIFT).
__global__ __launch_bounds__(256) void pe_hist_kernel(
    const int* __restrict__ c,
    unsigned* __restrict__ bucket_cnt,
    int num_edges, int nb) {
    __shared__ unsigned h[MAX_NB];
    const int tid = threadIdx.x;
    for (int b = tid; b < nb; b += 256) h[b] = 0u;
    __syncthreads();

    const int stride = gridDim.x * blockDim.x;
    const int gid = blockIdx.x * blockDim.x + tid;
    const int E4 = num_edges >> 2;
    for (int k = gid; k < E4; k += stride) {
        const int4 v = ((const int4*)c)[k];
        atomicAdd(&h[v.x >> NPB_SHIFT], 1u);
        atomicAdd(&h[v.y >> NPB_SHIFT], 1u);
        atomicAdd(&h[v.z >> NPB_SHIFT], 1u);
        atomicAdd(&h[v.w >> NPB_SHIFT], 1u);
    }
    for (int e = (E4 << 2) + gid; e < num_edges; e += stride)
        atomicAdd(&h[c[e] >> NPB_SHIFT], 1u);
    __syncthreads();

    for (int b = tid; b < nb; b += 256)
        if (h[b]) atomicAdd(&bucket_cnt[b], h[b]);
}

// Exclusive scan of bucket_cnt -> bucket_base[0..nb], gcursor = base.
__global__ __launch_bounds__(1024) void pe_scan_kernel(
    const unsigned* __restrict__ bucket_cnt,
    unsigned* __restrict__ bucket_base,
    unsigned* __restrict__ gcursor,
    int nb) {
    __shared__ unsigned s[MAX_NB];
    const int t = threadIdx.x;
    const unsigned v = (t < nb) ? bucket_cnt[t] : 0u;
    s[t] = v;
    __syncthreads();
    for (int off = 1; off < MAX_NB; off <<= 1) {
        const unsigned mine = s[t];
        const unsigned add = (t >= off) ? s[t - off] : 0u;
        __syncthreads();
        s[t] = mine + add;
        __syncthreads();
    }
    const unsigned excl = s[t] - v;
    if (t < nb) {
        bucket_base[t] = excl;
        gcursor[t] = excl;
    }
    if (t == 0) bucket_base[nb] = s[MAX_NB - 1];
}

// Bin kernel v2: LDS-staged indices + small chunk (2048 edges) for occupancy.
// Per block: coalesced int4 load of the chunk's c/u into LDS (one barrier),
// then 8 j-iterations of {ds_read indices -> 8 gathers -> dot/exp -> LDS count}
// with NO barrier inside the loop, so consecutive iterations' gathers overlap.
// Pairs are packed to 4B: [31:16] local node id (8b used), [15:0] f16 exp val.
__global__ __launch_bounds__(256) void pe_bin_kernel(
    const unsigned* __restrict__ Qq,
    const unsigned* __restrict__ Kq,
    const int* __restrict__ c,
    const int* __restrict__ u,
    unsigned* __restrict__ gcursor,
    unsigned* __restrict__ pairs,
    int num_edges, int nb) {
    __shared__ int lc[E1_CHUNK];
    __shared__ int lu[E1_CHUNK];
    __shared__ unsigned cnt[MAX_NB];
    __shared__ unsigned basesh[MAX_NB];

    const int tid = threadIdx.x;
    const int g4 = (tid >> 2) << 2;  // team's 4-edge offset within 256-edge slab
    const int sub = tid & 3;
    const int estart = blockIdx.x * E1_CHUNK;
    const int ecount = min(E1_CHUNK, num_edges - estart);
    const float inv_scale = 0.125f;  // 1/sqrt(64)

    for (int b = tid; b < nb; b += 256) cnt[b] = 0u;

    // stage chunk indices into LDS (coalesced; pad tail with node 0)
    for (int k = tid; k < (E1_CHUNK >> 2); k += 256) {
        const int e0 = k << 2;
        int4 vc, vu;
        if (e0 + 3 < ecount) {
            vc = ((const int4*)(c + estart))[k];
            vu = ((const int4*)(u + estart))[k];
        } else {
            vc.x = (e0 + 0 < ecount) ? c[estart + e0 + 0] : 0;
            vc.y = (e0 + 1 < ecount) ? c[estart + e0 + 1] : 0;
            vc.z = (e0 + 2 < ecount) ? c[estart + e0 + 2] : 0;
            vc.w = (e0 + 3 < ecount) ? c[estart + e0 + 3] : 0;
            vu.x = (e0 + 0 < ecount) ? u[estart + e0 + 0] : 0;
            vu.y = (e0 + 1 < ecount) ? u[estart + e0 + 1] : 0;
            vu.z = (e0 + 2 < ecount) ? u[estart + e0 + 2] : 0;
            vu.w = (e0 + 3 < ecount) ? u[estart + e0 + 3] : 0;
        }
        ((int4*)lc)[k] = vc;
        ((int4*)lu)[k] = vu;
    }
    __syncthreads();

    int pc[E1_EPT];       // node id (or -1 invalid)
    unsigned pw[E1_EPT];  // packed (local<<16)|f16
    int pr[E1_EPT];       // rank within (block, bucket)

#pragma unroll
    for (int j = 0; j < E1_EPT; ++j) {
        pc[j] = -1;
        const int base = j * 256;          // uniform across block
        const int tb = base + g4;
        const int4 ci = *(const int4*)(lc + tb);
        const int4 ui = *(const int4*)(lu + tb);

        const uint4 q0 = *(const uint4*)(Qq + (size_t)ci.x * 16 + sub * 4);
        const uint4 q1 = *(const uint4*)(Qq + (size_t)ci.y * 16 + sub * 4);
        const uint4 q2 = *(const uint4*)(Qq + (size_t)ci.z * 16 + sub * 4);
        const uint4 q3 = *(const uint4*)(Qq + (size_t)ci.w * 16 + sub * 4);
        const uint4 k0 = *(const uint4*)(Kq + (size_t)ui.x * 16 + sub * 4);
        const uint4 k1 = *(const uint4*)(Kq + (size_t)ui.y * 16 + sub * 4);
        const uint4 k2 = *(const uint4*)(Kq + (size_t)ui.z * 16 + sub * 4);
        const uint4 k3 = *(const uint4*)(Kq + (size_t)ui.w * 16 + sub * 4);

        const float d0 = red4(dot16_fp8(q0, k0));
        const float d1 = red4(dot16_fp8(q1, k1));
        const float d2 = red4(dot16_fp8(q2, k2));
        const float d3 = red4(dot16_fp8(q3, k3));

        const float dsel = (sub == 0) ? d0 : (sub == 1) ? d1 : (sub == 2) ? d2 : d3;
        const int csel = (sub == 0) ? ci.x : (sub == 1) ? ci.y : (sub == 2) ? ci.z : ci.w;

        // thread tid owns edge base + tid of the chunk
        if (base + tid < ecount) {
            pc[j] = csel;
            pw[j] = ((unsigned)(csel & (NPB - 1)) << 16) |
                    f32_to_f16bits(__expf(dsel * inv_scale));
            pr[j] = (int)atomicAdd(&cnt[csel >> NPB_SHIFT], 1u);
        }
    }
    __syncthreads();

    for (int b = tid; b < nb; b += 256) {
        const unsigned n = cnt[b];
        basesh[b] = n ? atomicAdd(&gcursor[b], n) : 0u;
    }
    __syncthreads();

#pragma unroll
    for (int j = 0; j < E1_EPT; ++j) {
        if (pc[j] >= 0) {
            const int b = pc[j] >> NPB_SHIFT;
            pairs[basesh[b] + (unsigned)pr[j]] = pw[j];
        }
    }
}

// Reduce kernel: one block per bucket. Stream the bucket's packed pairs,
// accumulate 256 node sums in LDS, then fused log + per-graph segment sum.
__global__ __launch_bounds__(256) void pe_reduce_kernel(
    const unsigned* __restrict__ pairs,
    const unsigned* __restrict__ bucket_base,
    const int* __restrict__ batch,
    float* __restrict__ out,
    int num_nodes) {
    __shared__ float acc[NPB];
    const int B = blockIdx.x;
    const int t = threadIdx.x;
    acc[t] = 0.0f;
    __syncthreads();

    const unsigned s0 = bucket_base[B];
    const unsigned s1 = bucket_base[B + 1];
    for (unsigned i = s0 + t; i < s1; i += 256) {
        const unsigned p = pairs[i];
        atomicAdd(&acc[p >> 16], f16bits_to_f32(p));
    }
    __syncthreads();

    const int node = (B << NPB_SHIFT) + t;
    const bool valid = node < num_nodes;
    const int nc = valid ? node : (num_nodes - 1);
    const float s = acc[t];
    float lse = (valid && s > 0.0f) ? logf(s) : 0.0f;
    const int b = batch[nc];

    const int b0 = __shfl(b, 0, 64);
    const bool uniform = __all(b == b0);
    if (uniform) {
        lse += __shfl_xor(lse, 1, 64);
        lse += __shfl_xor(lse, 2, 64);
        lse += __shfl_xor(lse, 4, 64);
        lse += __shfl_xor(lse, 8, 64);
        lse += __shfl_xor(lse, 16, 64);
        lse += __shfl_xor(lse, 32, 64);
        if ((t & 63) == 0 && lse != 0.0f) atomicAdd(&out[b0], lse);
    } else {
        if (valid && lse != 0.0f) atomicAdd(&out[b], lse);
    }
}

// ---------- fallback path (round-0 kernels, proven correct) ----------

__global__ __launch_bounds__(256) void pe_edge_kernel(
    const unsigned* __restrict__ Qq,
    const unsigned* __restrict__ Kq,
    const int* __restrict__ c,
    const int* __restrict__ u,
    float* __restrict__ node_sum,
    int num_edges) {
    const int tid = blockIdx.x * blockDim.x + threadIdx.x;
    const int group = tid >> 2;
    const int sub = tid & 3;
    const int ngroups = (gridDim.x * blockDim.x) >> 2;
    const float inv_scale = 0.125f;

    const int E4 = num_edges & ~3;

    for (int base = group * 4; base < E4; base += ngroups * 4) {
        const int4 ci = *(const int4*)(c + base);
        const int4 ui = *(const int4*)(u + base);

        const uint4 q0 = *(const uint4*)(Qq + (size_t)ci.x * 16 + sub * 4);
        const uint4 q1 = *(const uint4*)(Qq + (size_t)ci.y * 16 + sub * 4);
        const uint4 q2 = *(const uint4*)(Qq + (size_t)ci.z * 16 + sub * 4);
        const uint4 q3 = *(const uint4*)(Qq + (size_t)ci.w * 16 + sub * 4);
        const uint4 k0 = *(const uint4*)(Kq + (size_t)ui.x * 16 + sub * 4);
        const uint4 k1 = *(const uint4*)(Kq + (size_t)ui.y * 16 + sub * 4);
        const uint4 k2 = *(const uint4*)(Kq + (size_t)ui.z * 16 + sub * 4);
        const uint4 k3 = *(const uint4*)(Kq + (size_t)ui.w * 16 + sub * 4);

        float d0 = red4(dot16_fp8(q0, k0));
        float d1 = red4(dot16_fp8(q1, k1));
        float d2 = red4(dot16_fp8(q2, k2));
        float d3 = red4(dot16_fp8(q3, k3));

        const float dsel = (sub == 0) ? d0 : (sub == 1) ? d1 : (sub == 2) ? d2 : d3;
        const int csel = (sub == 0) ? ci.x : (sub == 1) ? ci.y : (sub == 2) ? ci.z : ci.w;
        atomicAdd(&node_sum[csel], __expf(dsel * inv_scale));
    }

    for (int e = E4 + group; e < num_edges; e += ngroups) {
        const int cc = c[e];
        const int uu = u[e];
        const uint4 q = *(const uint4*)(Qq + (size_t)cc * 16 + sub * 4);
        const uint4 k = *(const uint4*)(Kq + (size_t)uu * 16 + sub * 4);
        float d = red4(dot16_fp8(q, k));
        if (sub == 0) atomicAdd(&node_sum[cc], __expf(d * inv_scale));
    }
}

__global__ __launch_bounds__(256) void pe_node_kernel(
    const float* __restrict__ node_sum,
    const int* __restrict__ batch,
    float* __restrict__ out,
    int num_nodes) {
    const int n = blockIdx.x * blockDim.x + threadIdx.x;
    const bool valid = (n < num_nodes);
    const int nc = valid ? n : (num_nodes - 1);

    const float s = valid ? node_sum[nc] : 0.0f;
    float lse = (s > 0.0f) ? logf(s) : 0.0f;
    if (!valid) lse = 0.0f;
    const int b = batch[nc];

    const int b0 = __shfl(b, 0, 64);
    const bool uniform = __all(b == b0);
    if (uniform) {
        lse += __shfl_xor(lse, 1, 64);
        lse += __shfl_xor(lse, 2, 64);
        lse += __shfl_xor(lse, 4, 64);
        lse += __shfl_xor(lse, 8, 64);
        lse += __shfl_xor(lse, 16, 64);
        lse += __shfl_xor(lse, 32, 64);
        if ((threadIdx.x & 63) == 0 && lse != 0.0f) {
            atomicAdd(&out[b0], lse);
        }
    } else {
        if (valid && lse != 0.0f) {
            atomicAdd(&out[b], lse);
        }
    }
}

extern "C" void kernel_launch(void* const* d_in, const int* in_sizes, int n_in,
                              void* d_out, int out_size, void* d_ws, size_t ws_size,
                              hipStream_t stream) {
    const float* Q2 = (const float*)d_in[0];
    const float* K2 = (const float*)d_in[1];
    const int* c_2 = (const int*)d_in[2];
    const int* u_2 = (const int*)d_in[3];
    const int* batch = (const int*)d_in[4];

    const int num_nodes = in_sizes[4];
    const int num_edges = in_sizes[2];
    const int num_graphs = out_size;
    const int d = in_sizes[0] / num_nodes;   // 64
    const size_t row_elems = (size_t)num_nodes * d;
    const size_t row_bytes = row_elems;      // fp8: 1 B per element

    // ws layout: Qq | Kq | meta (bucket_cnt MAX_NB, bucket_base MAX_NB+1,
    //            gcursor MAX_NB, pad) | pairs (num_edges * 4 B)
    // fallback:  Qq | Kq | node_sum (num_nodes fp32)
    unsigned* Qq = (unsigned*)d_ws;
    unsigned* Kq = Qq + row_bytes / 4;
    unsigned* meta = Kq + row_bytes / 4;
    unsigned* bucket_cnt = meta;
    unsigned* bucket_base = meta + MAX_NB;
    unsigned* gcursor = bucket_base + MAX_NB + 1;
    unsigned* pairs = meta + 3 * MAX_NB + 16;
    float* node_sum = (float*)meta;
    float* out = (float*)d_out;

    const int nb = (num_nodes + NPB - 1) >> NPB_SHIFT;
    const size_t need_binned = row_bytes * 2 + (size_t)(3 * MAX_NB + 16) * 4 +
                               (size_t)num_edges * 4;
    const bool use_binned = (nb <= MAX_NB) && (ws_size >= need_binned) &&
                            (d == 64);

    // Pass 0: fp32 -> fp8 + fused zeroing
    {
        const int n4 = (int)(row_elems / 4);
        const int block = 256;
        const int grid = (n4 + block - 1) / block;
        pe_convert_kernel<<<grid, block, 0, stream>>>(
            Q2, K2, Qq, Kq,
            use_binned ? nullptr : node_sum,
            use_binned ? bucket_cnt : nullptr,
            out, n4, num_nodes, num_graphs);
    }

    if (use_binned) {
        pe_hist_kernel<<<256, 256, 0, stream>>>(c_2, bucket_cnt, num_edges, nb);
        pe_scan_kernel<<<1, 1024, 0, stream>>>(bucket_cnt, bucket_base, gcursor, nb);
        {
            const int grid = (num_edges + E1_CHUNK - 1) / E1_CHUNK;
            pe_bin_kernel<<<grid, 256, 0, stream>>>(Qq, Kq, c_2, u_2,
                                                    gcursor, pairs,
                                                    num_edges, nb);
        }
        pe_reduce_kernel<<<nb, 256, 0, stream>>>(pairs, bucket_base, batch,
                                                 out, num_nodes);
    } else {
        {
            const int block = 256;
            const int grid = 8192;
            pe_edge_kernel<<<grid, block, 0, stream>>>(Qq, Kq, c_2, u_2,
                                                       node_sum, num_edges);
        }
        {
            const int block = 256;
            const int grid = (num_nodes + block - 1) / block;
            pe_node_kernel<<<grid, block, 0, stream>>>(node_sum, batch, out,
                                                       num_nodes);
        }
    }
}

// Round 4
// 228.191 us; speedup vs baseline: 1.3394x; 1.2133x over previous
//
#include <hip/hip_runtime.h>
#include <hip/hip_fp8.h>
#include <math.h>

typedef __attribute__((ext_vector_type(2))) float fv2;

#if defined(__has_builtin)
#  if __has_builtin(__builtin_amdgcn_cvt_pk_f32_fp8) && \
      __has_builtin(__builtin_amdgcn_cvt_pk_fp8_f32)
#    define PE_HAVE_FP8_BUILTINS 1
#  endif
#endif

#define MAX_NB 1024          // max buckets supported by binned path
#define NPB 256              // nodes per bucket
#define NPB_SHIFT 8
#define B2_EPT 16            // edges per thread in binify
#define B2_CHUNK (B2_EPT * 256)   // 4096 edges per binify block
#define CPB 4                // chunks per bucket in dotred
#define RT 1024              // record tile (LDS staging) in dotred

// pack 4 floats -> 4 fp8 e4m3 bytes in one uint32
__device__ __forceinline__ unsigned pack4_fp8(float a, float b, float c, float d) {
#ifdef PE_HAVE_FP8_BUILTINS
    int w = 0;
    w = __builtin_amdgcn_cvt_pk_fp8_f32(a, b, w, false);  // bytes 0,1
    w = __builtin_amdgcn_cvt_pk_fp8_f32(c, d, w, true);   // bytes 2,3
    return (unsigned)w;
#else
    unsigned r = 0;
    r |= (unsigned)__hip_fp8_e4m3(a).__x;
    r |= (unsigned)__hip_fp8_e4m3(b).__x << 8;
    r |= (unsigned)__hip_fp8_e4m3(c).__x << 16;
    r |= (unsigned)__hip_fp8_e4m3(d).__x << 24;
    return r;
#endif
}

__device__ __forceinline__ float dot4w_fp8(unsigned qa, unsigned ka, float acc) {
#ifdef PE_HAVE_FP8_BUILTINS
    fv2 q0 = __builtin_amdgcn_cvt_pk_f32_fp8((int)qa, false);
    fv2 q1 = __builtin_amdgcn_cvt_pk_f32_fp8((int)qa, true);
    fv2 k0 = __builtin_amdgcn_cvt_pk_f32_fp8((int)ka, false);
    fv2 k1 = __builtin_amdgcn_cvt_pk_f32_fp8((int)ka, true);
    acc = fmaf(q0.x, k0.x, acc);
    acc = fmaf(q0.y, k0.y, acc);
    acc = fmaf(q1.x, k1.x, acc);
    acc = fmaf(q1.y, k1.y, acc);
    return acc;
#else
#pragma unroll
    for (int j = 0; j < 4; ++j) {
        __hip_fp8_e4m3 qv, kv;
        qv.__x = (qa >> (8 * j)) & 0xff;
        kv.__x = (ka >> (8 * j)) & 0xff;
        acc = fmaf((float)qv, (float)kv, acc);
    }
    return acc;
#endif
}

__device__ __forceinline__ float dot16_fp8(const uint4& q, const uint4& k) {
    float d = 0.0f;
    d = dot4w_fp8(q.x, k.x, d);
    d = dot4w_fp8(q.y, k.y, d);
    d = dot4w_fp8(q.z, k.z, d);
    d = dot4w_fp8(q.w, k.w, d);
    return d;
}

__device__ __forceinline__ float red4(float d) {
    d += __shfl_xor(d, 1, 64);
    d += __shfl_xor(d, 2, 64);
    return d;
}

// Pass 0: fp32 -> fp8 e4m3 rows; fused zeroing of out, node_sum, and
// bucket counters (binned path).
__global__ __launch_bounds__(256) void pe_convert_kernel(
    const float* __restrict__ Q,
    const float* __restrict__ K,
    unsigned* __restrict__ Qq,   // row = 16 uints = 64 fp8
    unsigned* __restrict__ Kq,
    float* __restrict__ node_sum,
    unsigned* __restrict__ bucket_cnt,// may be null (fallback path)
    float* __restrict__ out,
    int n4,           // total elements / 4
    int num_nodes,
    int num_graphs) {
    const int i = blockIdx.x * blockDim.x + threadIdx.x;
    if (i < num_nodes) node_sum[i] = 0.0f;
    if (bucket_cnt && i < MAX_NB) bucket_cnt[i] = 0u;
    if (i < num_graphs) out[i] = 0.0f;
    if (i >= n4) return;

    const float4 q = ((const float4*)Q)[i];
    const float4 k = ((const float4*)K)[i];
    Qq[i] = pack4_fp8(q.x, q.y, q.z, q.w);
    Kq[i] = pack4_fp8(k.x, k.y, k.z, k.w);
}

// Histogram of edge destinations by bucket (c >> NPB_SHIFT).
__global__ __launch_bounds__(256) void pe_hist_kernel(
    const int* __restrict__ c,
    unsigned* __restrict__ bucket_cnt,
    int num_edges, int nb) {
    __shared__ unsigned h[MAX_NB];
    const int tid = threadIdx.x;
    for (int b = tid; b < nb; b += 256) h[b] = 0u;
    __syncthreads();

    const int stride = gridDim.x * blockDim.x;
    const int gid = blockIdx.x * blockDim.x + tid;
    const int E4 = num_edges >> 2;
    for (int k = gid; k < E4; k += stride) {
        const int4 v = ((const int4*)c)[k];
        atomicAdd(&h[v.x >> NPB_SHIFT], 1u);
        atomicAdd(&h[v.y >> NPB_SHIFT], 1u);
        atomicAdd(&h[v.z >> NPB_SHIFT], 1u);
        atomicAdd(&h[v.w >> NPB_SHIFT], 1u);
    }
    for (int e = (E4 << 2) + gid; e < num_edges; e += stride)
        atomicAdd(&h[c[e] >> NPB_SHIFT], 1u);
    __syncthreads();

    for (int b = tid; b < nb; b += 256)
        if (h[b]) atomicAdd(&bucket_cnt[b], h[b]);
}

// Exclusive scan of bucket_cnt -> bucket_base[0..nb], gcursor = base.
__global__ __launch_bounds__(1024) void pe_scan_kernel(
    const unsigned* __restrict__ bucket_cnt,
    unsigned* __restrict__ bucket_base,
    unsigned* __restrict__ gcursor,
    int nb) {
    __shared__ unsigned s[MAX_NB];
    const int t = threadIdx.x;
    const unsigned v = (t < nb) ? bucket_cnt[t] : 0u;
    s[t] = v;
    __syncthreads();
    for (int off = 1; off < MAX_NB; off <<= 1) {
        const unsigned mine = s[t];
        const unsigned add = (t >= off) ? s[t - off] : 0u;
        __syncthreads();
        s[t] = mine + add;
        __syncthreads();
    }
    const unsigned excl = s[t] - v;
    if (t < nb) {
        bucket_base[t] = excl;
        gcursor[t] = excl;
    }
    if (t == 0) bucket_base[nb] = s[MAX_NB - 1];
}

// Binify: pure streaming, NO gathers, NO dots. Pack each edge as
// rec = (u << 8) | (c & 255) and scatter into bucket-grouped regions
// (per-block LDS counting + one returning cursor atomic per (block,bucket)).
__global__ __launch_bounds__(256) void pe_binify_kernel(
    const int* __restrict__ c,
    const int* __restrict__ u,
    unsigned* __restrict__ gcursor,
    unsigned* __restrict__ recs,
    int num_edges, int nb) {
    __shared__ unsigned cnt[MAX_NB];
    __shared__ unsigned basesh[MAX_NB];

    const int tid = threadIdx.x;
    const int estart = blockIdx.x * B2_CHUNK;

    for (int b = tid; b < nb; b += 256) cnt[b] = 0u;
    __syncthreads();

    unsigned rw[B2_EPT];  // packed record
    int rb[B2_EPT];       // bucket (or -1 invalid)
    int rr[B2_EPT];       // rank within (block, bucket)

#pragma unroll
    for (int j = 0; j < B2_EPT; ++j) {
        rb[j] = -1;
        const int e = estart + j * 256 + tid;   // coalesced per slab
        if (e < num_edges) {
            const int cc = c[e];
            const int uu = u[e];
            rb[j] = cc >> NPB_SHIFT;
            rw[j] = ((unsigned)uu << NPB_SHIFT) | (unsigned)(cc & (NPB - 1));
            rr[j] = (int)atomicAdd(&cnt[rb[j]], 1u);
        }
    }
    __syncthreads();

    for (int b = tid; b < nb; b += 256) {
        const unsigned n = cnt[b];
        basesh[b] = n ? atomicAdd(&gcursor[b], n) : 0u;
    }
    __syncthreads();

#pragma unroll
    for (int j = 0; j < B2_EPT; ++j) {
        if (rb[j] >= 0) recs[basesh[rb[j]] + (unsigned)rr[j]] = rw[j];
    }
}

// Dot-reduce: one block per (bucket, chunk). The bucket's 256 Q rows are
// CONTIGUOUS -> streamed into LDS once (16 KB, coalesced). Records are
// staged through a 4 KB LDS tile. Only the K-side gather stays random,
// over a hot set of just Kq (6.4 MB) -> much higher L2 hit rate than the
// old 12.8 MB two-sided random gather. exp accumulates in f32 LDS; one
// global f32 atomic per (block, touched node) at the end (~400k total).
__global__ __launch_bounds__(256) void pe_dotred_kernel(
    const unsigned* __restrict__ Qq,
    const unsigned* __restrict__ Kq,
    const unsigned* __restrict__ recs,
    const unsigned* __restrict__ bucket_base,
    float* __restrict__ node_sum,
    int num_nodes) {
    __shared__ uint4 qlds[NPB * 4];    // 16 KB: row-major, 4 uint4 per row
    __shared__ float acc[NPB];         // 1 KB
    __shared__ unsigned rlds[RT];      // 4 KB record tile

    const int B = blockIdx.x / CPB;
    const int chunk = blockIdx.x - B * CPB;
    const int t = threadIdx.x;
    const int g = t >> 2;              // team 0..63
    const int sub = t & 3;
    const float inv_scale = 0.125f;    // 1/sqrt(64)

    // stage this bucket's Q rows (contiguous, coalesced)
    const int nrows = min(NPB, num_nodes - B * NPB);
    const uint4* qsrc = (const uint4*)Qq + (size_t)B * NPB * 4;
    for (int i = t; i < nrows * 4; i += 256) qlds[i] = qsrc[i];
    acc[t] = 0.0f;

    const unsigned s0 = bucket_base[B];
    const unsigned len = bucket_base[B + 1] - s0;
    const unsigned r0 = s0 + (unsigned)(((unsigned long long)len * chunk) / CPB);
    const unsigned r1 = s0 + (unsigned)(((unsigned long long)len * (chunk + 1)) / CPB);

    for (unsigned t0 = r0; t0 < r1; t0 += RT) {
        const unsigned n = min((unsigned)RT, r1 - t0);
        __syncthreads();   // also covers initial qlds/acc stores
        for (unsigned i = t; i < n; i += 256) rlds[i] = recs[t0 + i];
        __syncthreads();
        for (unsigned i = g; i < n; i += 64) {
            const unsigned rec = rlds[i];            // LDS broadcast per team
            const unsigned uu = rec >> NPB_SHIFT;
            const unsigned local = rec & (NPB - 1);
            const uint4 k = *(const uint4*)(Kq + (size_t)uu * 16 + sub * 4);
            const uint4 q = qlds[local * 4 + sub];   // 2 lanes/bank: free
            const float d = red4(dot16_fp8(q, k));
            if (sub == 0) atomicAdd(&acc[local], __expf(d * inv_scale));
        }
    }
    __syncthreads();

    if (t < nrows && acc[t] != 0.0f)
        atomicAdd(&node_sum[B * NPB + t], acc[t]);
}

// Node pass: lse = log(node_sum[n]) (0 for empty), segment-sum into out.
__global__ __launch_bounds__(256) void pe_node_kernel(
    const float* __restrict__ node_sum,
    const int* __restrict__ batch,
    float* __restrict__ out,
    int num_nodes) {
    const int n = blockIdx.x * blockDim.x + threadIdx.x;
    const bool valid = (n < num_nodes);
    const int nc = valid ? n : (num_nodes - 1);

    const float s = valid ? node_sum[nc] : 0.0f;
    float lse = (s > 0.0f) ? logf(s) : 0.0f;
    if (!valid) lse = 0.0f;
    const int b = batch[nc];

    const int b0 = __shfl(b, 0, 64);
    const bool uniform = __all(b == b0);
    if (uniform) {
        lse += __shfl_xor(lse, 1, 64);
        lse += __shfl_xor(lse, 2, 64);
        lse += __shfl_xor(lse, 4, 64);
        lse += __shfl_xor(lse, 8, 64);
        lse += __shfl_xor(lse, 16, 64);
        lse += __shfl_xor(lse, 32, 64);
        if ((threadIdx.x & 63) == 0 && lse != 0.0f) {
            atomicAdd(&out[b0], lse);
        }
    } else {
        if (valid && lse != 0.0f) {
            atomicAdd(&out[b], lse);
        }
    }
}

// ---------- fallback path (round-0 edge kernel, proven correct) ----------

__global__ __launch_bounds__(256) void pe_edge_kernel(
    const unsigned* __restrict__ Qq,
    const unsigned* __restrict__ Kq,
    const int* __restrict__ c,
    const int* __restrict__ u,
    float* __restrict__ node_sum,
    int num_edges) {
    const int tid = blockIdx.x * blockDim.x + threadIdx.x;
    const int group = tid >> 2;
    const int sub = tid & 3;
    const int ngroups = (gridDim.x * blockDim.x) >> 2;
    const float inv_scale = 0.125f;

    const int E4 = num_edges & ~3;

    for (int base = group * 4; base < E4; base += ngroups * 4) {
        const int4 ci = *(const int4*)(c + base);
        const int4 ui = *(const int4*)(u + base);

        const uint4 q0 = *(const uint4*)(Qq + (size_t)ci.x * 16 + sub * 4);
        const uint4 q1 = *(const uint4*)(Qq + (size_t)ci.y * 16 + sub * 4);
        const uint4 q2 = *(const uint4*)(Qq + (size_t)ci.z * 16 + sub * 4);
        const uint4 q3 = *(const uint4*)(Qq + (size_t)ci.w * 16 + sub * 4);
        const uint4 k0 = *(const uint4*)(Kq + (size_t)ui.x * 16 + sub * 4);
        const uint4 k1 = *(const uint4*)(Kq + (size_t)ui.y * 16 + sub * 4);
        const uint4 k2 = *(const uint4*)(Kq + (size_t)ui.z * 16 + sub * 4);
        const uint4 k3 = *(const uint4*)(Kq + (size_t)ui.w * 16 + sub * 4);

        float d0 = red4(dot16_fp8(q0, k0));
        float d1 = red4(dot16_fp8(q1, k1));
        float d2 = red4(dot16_fp8(q2, k2));
        float d3 = red4(dot16_fp8(q3, k3));

        const float dsel = (sub == 0) ? d0 : (sub == 1) ? d1 : (sub == 2) ? d2 : d3;
        const int csel = (sub == 0) ? ci.x : (sub == 1) ? ci.y : (sub == 2) ? ci.z : ci.w;
        atomicAdd(&node_sum[csel], __expf(dsel * inv_scale));
    }

    for (int e = E4 + group; e < num_edges; e += ngroups) {
        const int cc = c[e];
        const int uu = u[e];
        const uint4 q = *(const uint4*)(Qq + (size_t)cc * 16 + sub * 4);
        const uint4 k = *(const uint4*)(Kq + (size_t)uu * 16 + sub * 4);
        float d = red4(dot16_fp8(q, k));
        if (sub == 0) atomicAdd(&node_sum[cc], __expf(d * inv_scale));
    }
}

extern "C" void kernel_launch(void* const* d_in, const int* in_sizes, int n_in,
                              void* d_out, int out_size, void* d_ws, size_t ws_size,
                              hipStream_t stream) {
    const float* Q2 = (const float*)d_in[0];
    const float* K2 = (const float*)d_in[1];
    const int* c_2 = (const int*)d_in[2];
    const int* u_2 = (const int*)d_in[3];
    const int* batch = (const int*)d_in[4];

    const int num_nodes = in_sizes[4];
    const int num_edges = in_sizes[2];
    const int num_graphs = out_size;
    const int d = in_sizes[0] / num_nodes;   // 64
    const size_t row_elems = (size_t)num_nodes * d;
    const size_t row_bytes = row_elems;      // fp8: 1 B per element

    // ws layout (binned): Qq | Kq | meta (bucket_cnt MAX_NB, bucket_base
    //   MAX_NB+1, gcursor MAX_NB, pad) | node_sum (num_nodes f32, 16-pad) |
    //   recs (num_edges u32)
    // fallback: Qq | Kq | node_sum (at meta)
    unsigned* Qq = (unsigned*)d_ws;
    unsigned* Kq = Qq + row_bytes / 4;
    unsigned* meta = Kq + row_bytes / 4;
    unsigned* bucket_cnt = meta;
    unsigned* bucket_base = meta + MAX_NB;
    unsigned* gcursor = bucket_base + MAX_NB + 1;
    float* node_sum_b = (float*)(meta + 3 * MAX_NB + 16);
    const size_t ns_pad = ((size_t)num_nodes + 15) & ~(size_t)15;
    unsigned* recs = (unsigned*)node_sum_b + ns_pad;
    float* node_sum_f = (float*)meta;        // fallback location
    float* out = (float*)d_out;

    const int nb = (num_nodes + NPB - 1) >> NPB_SHIFT;
    const size_t need_binned = row_bytes * 2 + (size_t)(3 * MAX_NB + 16) * 4 +
                               ns_pad * 4 + (size_t)num_edges * 4;
    const bool use_binned = (nb <= MAX_NB) && (ws_size >= need_binned) &&
                            (d == 64) && (num_nodes <= (1 << 24));

    float* node_sum = use_binned ? node_sum_b : node_sum_f;

    // Pass 0: fp32 -> fp8 + fused zeroing
    {
        const int n4 = (int)(row_elems / 4);
        const int block = 256;
        const int grid = (n4 + block - 1) / block;
        pe_convert_kernel<<<grid, block, 0, stream>>>(
            Q2, K2, Qq, Kq, node_sum,
            use_binned ? bucket_cnt : nullptr,
            out, n4, num_nodes, num_graphs);
    }

    if (use_binned) {
        pe_hist_kernel<<<256, 256, 0, stream>>>(c_2, bucket_cnt, num_edges, nb);
        pe_scan_kernel<<<1, 1024, 0, stream>>>(bucket_cnt, bucket_base, gcursor, nb);
        {
            const int grid = (num_edges + B2_CHUNK - 1) / B2_CHUNK;
            pe_binify_kernel<<<grid, 256, 0, stream>>>(c_2, u_2, gcursor, recs,
                                                       num_edges, nb);
        }
        pe_dotred_kernel<<<nb * CPB, 256, 0, stream>>>(Qq, Kq, recs, bucket_base,
                                                       node_sum, num_nodes);
    } else {
        pe_edge_kernel<<<8192, 256, 0, stream>>>(Qq, Kq, c_2, u_2,
                                                 node_sum, num_edges);
    }

    // Final pass: log + per-graph sum
    {
        const int block = 256;
        const int grid = (num_nodes + block - 1) / block;
        pe_node_kernel<<<grid, block, 0, stream>>>(node_sum, batch, out,
                                                   num_nodes);
    }
}

// Round 5
// 216.146 us; speedup vs baseline: 1.4141x; 1.0557x over previous
//
#include <hip/hip_runtime.h>
#include <hip/hip_fp8.h>
#include <math.h>

typedef __attribute__((ext_vector_type(2))) float fv2;

#if defined(__has_builtin)
#  if __has_builtin(__builtin_amdgcn_cvt_pk_f32_fp8) && \
      __has_builtin(__builtin_amdgcn_cvt_pk_fp8_f32)
#    define PE_HAVE_FP8_BUILTINS 1
#  endif
#endif

#define MAX_NB 1024          // max buckets supported by binned path
#define NPB 256              // nodes per bucket
#define NPB_SHIFT 8
#define B2_EPT 16            // edges per thread in count/binify
#define B2_CHUNK (B2_EPT * 256)   // 4096 edges per block
#define CPB 8                // chunks per bucket in dotred
#define RT 1024              // record tile (LDS staging) in dotred

// pack 4 floats -> 4 fp8 e4m3 bytes in one uint32
__device__ __forceinline__ unsigned pack4_fp8(float a, float b, float c, float d) {
#ifdef PE_HAVE_FP8_BUILTINS
    int w = 0;
    w = __builtin_amdgcn_cvt_pk_fp8_f32(a, b, w, false);  // bytes 0,1
    w = __builtin_amdgcn_cvt_pk_fp8_f32(c, d, w, true);   // bytes 2,3
    return (unsigned)w;
#else
    unsigned r = 0;
    r |= (unsigned)__hip_fp8_e4m3(a).__x;
    r |= (unsigned)__hip_fp8_e4m3(b).__x << 8;
    r |= (unsigned)__hip_fp8_e4m3(c).__x << 16;
    r |= (unsigned)__hip_fp8_e4m3(d).__x << 24;
    return r;
#endif
}

__device__ __forceinline__ float dot4w_fp8(unsigned qa, unsigned ka, float acc) {
#ifdef PE_HAVE_FP8_BUILTINS
    fv2 q0 = __builtin_amdgcn_cvt_pk_f32_fp8((int)qa, false);
    fv2 q1 = __builtin_amdgcn_cvt_pk_f32_fp8((int)qa, true);
    fv2 k0 = __builtin_amdgcn_cvt_pk_f32_fp8((int)ka, false);
    fv2 k1 = __builtin_amdgcn_cvt_pk_f32_fp8((int)ka, true);
    acc = fmaf(q0.x, k0.x, acc);
    acc = fmaf(q0.y, k0.y, acc);
    acc = fmaf(q1.x, k1.x, acc);
    acc = fmaf(q1.y, k1.y, acc);
    return acc;
#else
#pragma unroll
    for (int j = 0; j < 4; ++j) {
        __hip_fp8_e4m3 qv, kv;
        qv.__x = (qa >> (8 * j)) & 0xff;
        kv.__x = (ka >> (8 * j)) & 0xff;
        acc = fmaf((float)qv, (float)kv, acc);
    }
    return acc;
#endif
}

__device__ __forceinline__ float dot16_fp8(const uint4& q, const uint4& k) {
    float d = 0.0f;
    d = dot4w_fp8(q.x, k.x, d);
    d = dot4w_fp8(q.y, k.y, d);
    d = dot4w_fp8(q.z, k.z, d);
    d = dot4w_fp8(q.w, k.w, d);
    return d;
}

__device__ __forceinline__ float red4(float d) {
    d += __shfl_xor(d, 1, 64);
    d += __shfl_xor(d, 2, 64);
    return d;
}

// Pass 0: fp32 -> fp8 e4m3 rows; fused zeroing of out and node_sum.
__global__ __launch_bounds__(256) void pe_convert_kernel(
    const float* __restrict__ Q,
    const float* __restrict__ K,
    unsigned* __restrict__ Qq,   // row = 16 uints = 64 fp8
    unsigned* __restrict__ Kq,
    float* __restrict__ node_sum,
    float* __restrict__ out,
    int n4,           // total elements / 4
    int num_nodes,
    int num_graphs) {
    const int i = blockIdx.x * blockDim.x + threadIdx.x;
    if (i < num_nodes) node_sum[i] = 0.0f;
    if (i < num_graphs) out[i] = 0.0f;
    if (i >= n4) return;

    const float4 q = ((const float4*)Q)[i];
    const float4 k = ((const float4*)K)[i];
    Qq[i] = pack4_fp8(q.x, q.y, q.z, q.w);
    Kq[i] = pack4_fp8(k.x, k.y, k.z, k.w);
}

// Count: per-chunk LDS histogram of destination buckets -> cnt_mat[b][blk].
// Replaces the global hist kernel AND removes the need for cursor atomics.
__global__ __launch_bounds__(256) void pe_count_kernel(
    const int* __restrict__ c,
    unsigned* __restrict__ cnt_mat,   // [nb][nblk]
    int num_edges, int nb, int nblk) {
    __shared__ unsigned h[MAX_NB];
    const int tid = threadIdx.x;
    const int blk = blockIdx.x;
    for (int b = tid; b < nb; b += 256) h[b] = 0u;
    __syncthreads();

    const int estart = blk * B2_CHUNK;
    const int ecount = min(B2_CHUNK, num_edges - estart);
    const int n4 = ecount >> 2;
    const int4* c4 = (const int4*)(c + estart);
    for (int k = tid; k < n4; k += 256) {
        const int4 v = c4[k];
        atomicAdd(&h[v.x >> NPB_SHIFT], 1u);
        atomicAdd(&h[v.y >> NPB_SHIFT], 1u);
        atomicAdd(&h[v.z >> NPB_SHIFT], 1u);
        atomicAdd(&h[v.w >> NPB_SHIFT], 1u);
    }
    for (int e = (n4 << 2) + tid; e < ecount; e += 256)
        atomicAdd(&h[c[estart + e] >> NPB_SHIFT], 1u);
    __syncthreads();

    for (int b = tid; b < nb; b += 256)
        cnt_mat[(size_t)b * nblk + blk] = h[b];
}

// Per-bucket exclusive scan over blocks (in place) + bucket totals.
// One block per bucket; tiles of 256 with running carry.
__global__ __launch_bounds__(256) void pe_matscan_kernel(
    unsigned* __restrict__ cnt_mat,
    unsigned* __restrict__ bucket_cnt,
    int nblk) {
    __shared__ unsigned s[256];
    const int t = threadIdx.x;
    unsigned* row = cnt_mat + (size_t)blockIdx.x * nblk;
    unsigned carry = 0u;
    for (int t0 = 0; t0 < nblk; t0 += 256) {
        const int i = t0 + t;
        const unsigned v = (i < nblk) ? row[i] : 0u;
        s[t] = v;
        __syncthreads();
        for (int off = 1; off < 256; off <<= 1) {
            const unsigned mine = s[t];
            const unsigned add = (t >= off) ? s[t - off] : 0u;
            __syncthreads();
            s[t] = mine + add;
            __syncthreads();
        }
        if (i < nblk) row[i] = carry + (s[t] - v);   // exclusive + carry
        carry += s[255];
        __syncthreads();
    }
    if (t == 0) bucket_cnt[blockIdx.x] = carry;
}

// Exclusive scan of bucket_cnt -> bucket_base[0..nb].
__global__ __launch_bounds__(1024) void pe_scan_kernel(
    const unsigned* __restrict__ bucket_cnt,
    unsigned* __restrict__ bucket_base,
    int nb) {
    __shared__ unsigned s[MAX_NB];
    const int t = threadIdx.x;
    const unsigned v = (t < nb) ? bucket_cnt[t] : 0u;
    s[t] = v;
    __syncthreads();
    for (int off = 1; off < MAX_NB; off <<= 1) {
        const unsigned mine = s[t];
        const unsigned add = (t >= off) ? s[t - off] : 0u;
        __syncthreads();
        s[t] = mine + add;
        __syncthreads();
    }
    if (t < nb) bucket_base[t] = s[t] - v;
    if (t == 0) bucket_base[nb] = s[MAX_NB - 1];
}

// Binify v2: fully deterministic scatter — ZERO global atomics. Each block's
// per-bucket output base = bucket_base[b] + cnt_mat[b][blk] (plain coalesced
// loads). Only per-block LDS rank atomics remain. int4 index loads.
__global__ __launch_bounds__(256) void pe_binify_kernel(
    const int* __restrict__ c,
    const int* __restrict__ u,
    const unsigned* __restrict__ cnt_mat,    // exclusive per-bucket scans
    const unsigned* __restrict__ bucket_base,
    unsigned* __restrict__ recs,
    int num_edges, int nb, int nblk) {
    __shared__ unsigned rank[MAX_NB];
    __shared__ unsigned basesh[MAX_NB];

    const int tid = threadIdx.x;
    const int blk = blockIdx.x;
    const int estart = blk * B2_CHUNK;
    const int ecount = min(B2_CHUNK, num_edges - estart);

    for (int b = tid; b < nb; b += 256) {
        rank[b] = 0u;
        basesh[b] = bucket_base[b] + cnt_mat[(size_t)b * nblk + blk];
    }
    __syncthreads();

    unsigned rw[B2_EPT];  // packed record (u << 8) | (c & 255)
    int rb[B2_EPT];       // bucket (or -1 invalid)
    unsigned rr[B2_EPT];  // rank within (block, bucket)

    if (ecount == B2_CHUNK) {
        const int4* c4 = (const int4*)(c + estart);
        const int4* u4 = (const int4*)(u + estart);
#pragma unroll
        for (int jj = 0; jj < 4; ++jj) {
            const int k = jj * 256 + tid;
            const int4 cv = c4[k];
            const int4 uv = u4[k];
            const int j = jj * 4;
            rb[j + 0] = cv.x >> NPB_SHIFT;
            rb[j + 1] = cv.y >> NPB_SHIFT;
            rb[j + 2] = cv.z >> NPB_SHIFT;
            rb[j + 3] = cv.w >> NPB_SHIFT;
            rw[j + 0] = ((unsigned)uv.x << NPB_SHIFT) | (unsigned)(cv.x & (NPB - 1));
            rw[j + 1] = ((unsigned)uv.y << NPB_SHIFT) | (unsigned)(cv.y & (NPB - 1));
            rw[j + 2] = ((unsigned)uv.z << NPB_SHIFT) | (unsigned)(cv.z & (NPB - 1));
            rw[j + 3] = ((unsigned)uv.w << NPB_SHIFT) | (unsigned)(cv.w & (NPB - 1));
            rr[j + 0] = atomicAdd(&rank[rb[j + 0]], 1u);
            rr[j + 1] = atomicAdd(&rank[rb[j + 1]], 1u);
            rr[j + 2] = atomicAdd(&rank[rb[j + 2]], 1u);
            rr[j + 3] = atomicAdd(&rank[rb[j + 3]], 1u);
        }
    } else {
#pragma unroll
        for (int j = 0; j < B2_EPT; ++j) {
            rb[j] = -1;
            const int e = estart + j * 256 + tid;
            if (e < num_edges) {
                const int cc = c[e];
                const int uu = u[e];
                rb[j] = cc >> NPB_SHIFT;
                rw[j] = ((unsigned)uu << NPB_SHIFT) | (unsigned)(cc & (NPB - 1));
                rr[j] = atomicAdd(&rank[rb[j]], 1u);
            }
        }
    }

    // no barrier needed: each thread consumes only its own returned ranks
#pragma unroll
    for (int j = 0; j < B2_EPT; ++j) {
        if (rb[j] >= 0) recs[basesh[rb[j]] + rr[j]] = rw[j];
    }
}

// Dot-reduce: one block per (bucket, chunk). Bucket's 256 Q rows contiguous
// -> streamed into LDS once. Records staged through a 4 KB LDS tile. Only
// the K gather stays random (hot set = Kq, 6.4 MB). exp accumulates in f32
// LDS; one global f32 atomic per (block, touched node) at the end.
__global__ __launch_bounds__(256) void pe_dotred_kernel(
    const unsigned* __restrict__ Qq,
    const unsigned* __restrict__ Kq,
    const unsigned* __restrict__ recs,
    const unsigned* __restrict__ bucket_base,
    float* __restrict__ node_sum,
    int num_nodes) {
    __shared__ uint4 qlds[NPB * 4];    // 16 KB: row-major, 4 uint4 per row
    __shared__ float acc[NPB];         // 1 KB
    __shared__ unsigned rlds[RT];      // 4 KB record tile

    const int B = blockIdx.x / CPB;
    const int chunk = blockIdx.x - B * CPB;
    const int t = threadIdx.x;
    const int g = t >> 2;              // team 0..63
    const int sub = t & 3;
    const float inv_scale = 0.125f;    // 1/sqrt(64)

    // stage this bucket's Q rows (contiguous, coalesced)
    const int nrows = min(NPB, num_nodes - B * NPB);
    const uint4* qsrc = (const uint4*)Qq + (size_t)B * NPB * 4;
    for (int i = t; i < nrows * 4; i += 256) qlds[i] = qsrc[i];
    acc[t] = 0.0f;

    const unsigned s0 = bucket_base[B];
    const unsigned len = bucket_base[B + 1] - s0;
    const unsigned r0 = s0 + (unsigned)(((unsigned long long)len * chunk) / CPB);
    const unsigned r1 = s0 + (unsigned)(((unsigned long long)len * (chunk + 1)) / CPB);

    for (unsigned t0 = r0; t0 < r1; t0 += RT) {
        const unsigned n = min((unsigned)RT, r1 - t0);
        __syncthreads();   // also covers initial qlds/acc stores
        for (unsigned i = t; i < n; i += 256) rlds[i] = recs[t0 + i];
        __syncthreads();
        for (unsigned i = g; i < n; i += 64) {
            const unsigned rec = rlds[i];            // LDS broadcast per team
            const unsigned uu = rec >> NPB_SHIFT;
            const unsigned local = rec & (NPB - 1);
            const uint4 k = *(const uint4*)(Kq + (size_t)uu * 16 + sub * 4);
            const uint4 q = qlds[local * 4 + sub];   // 2 lanes/bank: free
            const float d = red4(dot16_fp8(q, k));
            if (sub == 0) atomicAdd(&acc[local], __expf(d * inv_scale));
        }
    }
    __syncthreads();

    if (t < nrows && acc[t] != 0.0f)
        atomicAdd(&node_sum[B * NPB + t], acc[t]);
}

// Node pass: lse = log(node_sum[n]) (0 for empty), segment-sum into out.
__global__ __launch_bounds__(256) void pe_node_kernel(
    const float* __restrict__ node_sum,
    const int* __restrict__ batch,
    float* __restrict__ out,
    int num_nodes) {
    const int n = blockIdx.x * blockDim.x + threadIdx.x;
    const bool valid = (n < num_nodes);
    const int nc = valid ? n : (num_nodes - 1);

    const float s = valid ? node_sum[nc] : 0.0f;
    float lse = (s > 0.0f) ? logf(s) : 0.0f;
    if (!valid) lse = 0.0f;
    const int b = batch[nc];

    const int b0 = __shfl(b, 0, 64);
    const bool uniform = __all(b == b0);
    if (uniform) {
        lse += __shfl_xor(lse, 1, 64);
        lse += __shfl_xor(lse, 2, 64);
        lse += __shfl_xor(lse, 4, 64);
        lse += __shfl_xor(lse, 8, 64);
        lse += __shfl_xor(lse, 16, 64);
        lse += __shfl_xor(lse, 32, 64);
        if ((threadIdx.x & 63) == 0 && lse != 0.0f) {
            atomicAdd(&out[b0], lse);
        }
    } else {
        if (valid && lse != 0.0f) {
            atomicAdd(&out[b], lse);
        }
    }
}

// ---------- fallback path (round-0 edge kernel, proven correct) ----------

__global__ __launch_bounds__(256) void pe_edge_kernel(
    const unsigned* __restrict__ Qq,
    const unsigned* __restrict__ Kq,
    const int* __restrict__ c,
    const int* __restrict__ u,
    float* __restrict__ node_sum,
    int num_edges) {
    const int tid = blockIdx.x * blockDim.x + threadIdx.x;
    const int group = tid >> 2;
    const int sub = tid & 3;
    const int ngroups = (gridDim.x * blockDim.x) >> 2;
    const float inv_scale = 0.125f;

    const int E4 = num_edges & ~3;

    for (int base = group * 4; base < E4; base += ngroups * 4) {
        const int4 ci = *(const int4*)(c + base);
        const int4 ui = *(const int4*)(u + base);

        const uint4 q0 = *(const uint4*)(Qq + (size_t)ci.x * 16 + sub * 4);
        const uint4 q1 = *(const uint4*)(Qq + (size_t)ci.y * 16 + sub * 4);
        const uint4 q2 = *(const uint4*)(Qq + (size_t)ci.z * 16 + sub * 4);
        const uint4 q3 = *(const uint4*)(Qq + (size_t)ci.w * 16 + sub * 4);
        const uint4 k0 = *(const uint4*)(Kq + (size_t)ui.x * 16 + sub * 4);
        const uint4 k1 = *(const uint4*)(Kq + (size_t)ui.y * 16 + sub * 4);
        const uint4 k2 = *(const uint4*)(Kq + (size_t)ui.z * 16 + sub * 4);
        const uint4 k3 = *(const uint4*)(Kq + (size_t)ui.w * 16 + sub * 4);

        float d0 = red4(dot16_fp8(q0, k0));
        float d1 = red4(dot16_fp8(q1, k1));
        float d2 = red4(dot16_fp8(q2, k2));
        float d3 = red4(dot16_fp8(q3, k3));

        const float dsel = (sub == 0) ? d0 : (sub == 1) ? d1 : (sub == 2) ? d2 : d3;
        const int csel = (sub == 0) ? ci.x : (sub == 1) ? ci.y : (sub == 2) ? ci.z : ci.w;
        atomicAdd(&node_sum[csel], __expf(dsel * inv_scale));
    }

    for (int e = E4 + group; e < num_edges; e += ngroups) {
        const int cc = c[e];
        const int uu = u[e];
        const uint4 q = *(const uint4*)(Qq + (size_t)cc * 16 + sub * 4);
        const uint4 k = *(const uint4*)(Kq + (size_t)uu * 16 + sub * 4);
        float d = red4(dot16_fp8(q, k));
        if (sub == 0) atomicAdd(&node_sum[cc], __expf(d * inv_scale));
    }
}

extern "C" void kernel_launch(void* const* d_in, const int* in_sizes, int n_in,
                              void* d_out, int out_size, void* d_ws, size_t ws_size,
                              hipStream_t stream) {
    const float* Q2 = (const float*)d_in[0];
    const float* K2 = (const float*)d_in[1];
    const int* c_2 = (const int*)d_in[2];
    const int* u_2 = (const int*)d_in[3];
    const int* batch = (const int*)d_in[4];

    const int num_nodes = in_sizes[4];
    const int num_edges = in_sizes[2];
    const int num_graphs = out_size;
    const int d = in_sizes[0] / num_nodes;   // 64
    const size_t row_elems = (size_t)num_nodes * d;
    const size_t row_bytes = row_elems;      // fp8: 1 B per element

    const int nb = (num_nodes + NPB - 1) >> NPB_SHIFT;
    const int nblk = (num_edges + B2_CHUNK - 1) / B2_CHUNK;

    // ws layout (binned): Qq | Kq | meta (bucket_cnt MAX_NB, bucket_base
    //   MAX_NB+1, pad) | node_sum (ns_pad f32) | recs (E u32) |
    //   cnt_mat (nb*nblk u32)
    // fallback: Qq | Kq | node_sum (at meta)
    unsigned* Qq = (unsigned*)d_ws;
    unsigned* Kq = Qq + row_bytes / 4;
    unsigned* meta = Kq + row_bytes / 4;
    unsigned* bucket_cnt = meta;
    unsigned* bucket_base = meta + MAX_NB;
    float* node_sum_b = (float*)(meta + 2 * MAX_NB + 16);
    const size_t ns_pad = ((size_t)num_nodes + 15) & ~(size_t)15;
    unsigned* recs = (unsigned*)node_sum_b + ns_pad;
    unsigned* cnt_mat = recs + num_edges;
    float* node_sum_f = (float*)meta;        // fallback location
    float* out = (float*)d_out;

    const size_t need_binned = row_bytes * 2 + (size_t)(2 * MAX_NB + 16) * 4 +
                               ns_pad * 4 + (size_t)num_edges * 4 +
                               (size_t)nb * nblk * 4;
    const bool use_binned = (nb <= MAX_NB) && (ws_size >= need_binned) &&
                            (d == 64) && (num_nodes <= (1 << 24));

    float* node_sum = use_binned ? node_sum_b : node_sum_f;

    // Pass 0: fp32 -> fp8 + fused zeroing
    {
        const int n4 = (int)(row_elems / 4);
        const int block = 256;
        const int grid = (n4 + block - 1) / block;
        pe_convert_kernel<<<grid, block, 0, stream>>>(
            Q2, K2, Qq, Kq, node_sum, out, n4, num_nodes, num_graphs);
    }

    if (use_binned) {
        pe_count_kernel<<<nblk, 256, 0, stream>>>(c_2, cnt_mat,
                                                  num_edges, nb, nblk);
        pe_matscan_kernel<<<nb, 256, 0, stream>>>(cnt_mat, bucket_cnt, nblk);
        pe_scan_kernel<<<1, 1024, 0, stream>>>(bucket_cnt, bucket_base, nb);
        pe_binify_kernel<<<nblk, 256, 0, stream>>>(c_2, u_2, cnt_mat,
                                                   bucket_base, recs,
                                                   num_edges, nb, nblk);
        pe_dotred_kernel<<<nb * CPB, 256, 0, stream>>>(Qq, Kq, recs,
                                                       bucket_base,
                                                       node_sum, num_nodes);
    } else {
        pe_edge_kernel<<<8192, 256, 0, stream>>>(Qq, Kq, c_2, u_2,
                                                 node_sum, num_edges);
    }

    // Final pass: log + per-graph sum
    {
        const int block = 256;
        const int grid = (num_nodes + block - 1) / block;
        pe_node_kernel<<<grid, block, 0, stream>>>(node_sum, batch, out,
                                                   num_nodes);
    }
}

// Round 6
// 197.757 us; speedup vs baseline: 1.5455x; 1.0930x over previous
//
#include <hip/hip_runtime.h>
#include <hip/hip_fp8.h>
#include <math.h>

typedef __attribute__((ext_vector_type(2))) float fv2;

#if defined(__has_builtin)
#  if __has_builtin(__builtin_amdgcn_cvt_pk_f32_fp8) && \
      __has_builtin(__builtin_amdgcn_cvt_pk_fp8_f32)
#    define PE_HAVE_FP8_BUILTINS 1
#  endif
#endif

#define MAX_NB 1024          // max buckets supported by binned path
#define NPB 256              // nodes per bucket
#define NPB_SHIFT 8
#define B2_EPT 16            // edges per thread in count/binify
#define B2_CHUNK (B2_EPT * 256)   // 4096 edges per block
#define CPB 4                // chunks per bucket in dotred
#define RT 1024              // record tile (LDS staging) in dotred
#define NXCD 8

// pack 4 floats -> 4 fp8 e4m3 bytes in one uint32
__device__ __forceinline__ unsigned pack4_fp8(float a, float b, float c, float d) {
#ifdef PE_HAVE_FP8_BUILTINS
    int w = 0;
    w = __builtin_amdgcn_cvt_pk_fp8_f32(a, b, w, false);  // bytes 0,1
    w = __builtin_amdgcn_cvt_pk_fp8_f32(c, d, w, true);   // bytes 2,3
    return (unsigned)w;
#else
    unsigned r = 0;
    r |= (unsigned)__hip_fp8_e4m3(a).__x;
    r |= (unsigned)__hip_fp8_e4m3(b).__x << 8;
    r |= (unsigned)__hip_fp8_e4m3(c).__x << 16;
    r |= (unsigned)__hip_fp8_e4m3(d).__x << 24;
    return r;
#endif
}

__device__ __forceinline__ float dot4w_fp8(unsigned qa, unsigned ka, float acc) {
#ifdef PE_HAVE_FP8_BUILTINS
    fv2 q0 = __builtin_amdgcn_cvt_pk_f32_fp8((int)qa, false);
    fv2 q1 = __builtin_amdgcn_cvt_pk_f32_fp8((int)qa, true);
    fv2 k0 = __builtin_amdgcn_cvt_pk_f32_fp8((int)ka, false);
    fv2 k1 = __builtin_amdgcn_cvt_pk_f32_fp8((int)ka, true);
    acc = fmaf(q0.x, k0.x, acc);
    acc = fmaf(q0.y, k0.y, acc);
    acc = fmaf(q1.x, k1.x, acc);
    acc = fmaf(q1.y, k1.y, acc);
    return acc;
#else
#pragma unroll
    for (int j = 0; j < 4; ++j) {
        __hip_fp8_e4m3 qv, kv;
        qv.__x = (qa >> (8 * j)) & 0xff;
        kv.__x = (ka >> (8 * j)) & 0xff;
        acc = fmaf((float)qv, (float)kv, acc);
    }
    return acc;
#endif
}

__device__ __forceinline__ float dot16_fp8(const uint4& q, const uint4& k) {
    float d = 0.0f;
    d = dot4w_fp8(q.x, k.x, d);
    d = dot4w_fp8(q.y, k.y, d);
    d = dot4w_fp8(q.z, k.z, d);
    d = dot4w_fp8(q.w, k.w, d);
    return d;
}

__device__ __forceinline__ float red4(float d) {
    d += __shfl_xor(d, 1, 64);
    d += __shfl_xor(d, 2, 64);
    return d;
}

// Pass 0: fp32 -> fp8 e4m3 rows; fused zeroing of out and node_sum.
__global__ __launch_bounds__(256) void pe_convert_kernel(
    const float* __restrict__ Q,
    const float* __restrict__ K,
    unsigned* __restrict__ Qq,   // row = 16 uints = 64 fp8
    unsigned* __restrict__ Kq,
    float* __restrict__ node_sum,
    float* __restrict__ out,
    int n4,           // total elements / 4
    int num_nodes,
    int num_graphs) {
    const int i = blockIdx.x * blockDim.x + threadIdx.x;
    if (i < num_nodes) node_sum[i] = 0.0f;
    if (i < num_graphs) out[i] = 0.0f;
    if (i >= n4) return;

    const float4 q = ((const float4*)Q)[i];
    const float4 k = ((const float4*)K)[i];
    Qq[i] = pack4_fp8(q.x, q.y, q.z, q.w);
    Kq[i] = pack4_fp8(k.x, k.y, k.z, k.w);
}

// Count: per-chunk LDS histogram of destination buckets -> cnt_mat[b][blk].
__global__ __launch_bounds__(256) void pe_count_kernel(
    const int* __restrict__ c,
    unsigned* __restrict__ cnt_mat,   // [nb][nblk]
    int num_edges, int nb, int nblk) {
    __shared__ unsigned h[MAX_NB];
    const int tid = threadIdx.x;
    const int blk = blockIdx.x;
    for (int b = tid; b < nb; b += 256) h[b] = 0u;
    __syncthreads();

    const int estart = blk * B2_CHUNK;
    const int ecount = min(B2_CHUNK, num_edges - estart);
    const int n4 = ecount >> 2;
    const int4* c4 = (const int4*)(c + estart);
    for (int k = tid; k < n4; k += 256) {
        const int4 v = c4[k];
        atomicAdd(&h[v.x >> NPB_SHIFT], 1u);
        atomicAdd(&h[v.y >> NPB_SHIFT], 1u);
        atomicAdd(&h[v.z >> NPB_SHIFT], 1u);
        atomicAdd(&h[v.w >> NPB_SHIFT], 1u);
    }
    for (int e = (n4 << 2) + tid; e < ecount; e += 256)
        atomicAdd(&h[c[estart + e] >> NPB_SHIFT], 1u);
    __syncthreads();

    for (int b = tid; b < nb; b += 256)
        cnt_mat[(size_t)b * nblk + blk] = h[b];
}

// Per-bucket exclusive scan over blocks (in place) + bucket totals.
__global__ __launch_bounds__(256) void pe_matscan_kernel(
    unsigned* __restrict__ cnt_mat,
    unsigned* __restrict__ bucket_cnt,
    int nblk) {
    __shared__ unsigned s[256];
    const int t = threadIdx.x;
    unsigned* row = cnt_mat + (size_t)blockIdx.x * nblk;
    unsigned carry = 0u;
    for (int t0 = 0; t0 < nblk; t0 += 256) {
        const int i = t0 + t;
        const unsigned v = (i < nblk) ? row[i] : 0u;
        s[t] = v;
        __syncthreads();
        for (int off = 1; off < 256; off <<= 1) {
            const unsigned mine = s[t];
            const unsigned add = (t >= off) ? s[t - off] : 0u;
            __syncthreads();
            s[t] = mine + add;
            __syncthreads();
        }
        if (i < nblk) row[i] = carry + (s[t] - v);   // exclusive + carry
        carry += s[255];
        __syncthreads();
    }
    if (t == 0) bucket_cnt[blockIdx.x] = carry;
}

// Exclusive scan of bucket_cnt -> bucket_base[0..nb].
__global__ __launch_bounds__(1024) void pe_scan_kernel(
    const unsigned* __restrict__ bucket_cnt,
    unsigned* __restrict__ bucket_base,
    int nb) {
    __shared__ unsigned s[MAX_NB];
    const int t = threadIdx.x;
    const unsigned v = (t < nb) ? bucket_cnt[t] : 0u;
    s[t] = v;
    __syncthreads();
    for (int off = 1; off < MAX_NB; off <<= 1) {
        const unsigned mine = s[t];
        const unsigned add = (t >= off) ? s[t - off] : 0u;
        __syncthreads();
        s[t] = mine + add;
        __syncthreads();
    }
    if (t < nb) bucket_base[t] = s[t] - v;
    if (t == 0) bucket_base[nb] = s[MAX_NB - 1];
}

// Binify v3: deterministic scatter with LDS REORDER so global writes are
// coalesced runs. Phases: (1) rank via LDS atomics; (2) block-local
// exclusive scan of bucket counts (wave shfl scan); (3) scatter records
// into LDS in bucket-major order; (4) linear write-out — consecutive
// threads hit consecutive addresses within each per-bucket run (~10 recs),
// cutting store line-touches ~8x vs per-record random scatter.
__global__ __launch_bounds__(256) void pe_binify_kernel(
    const int* __restrict__ c,
    const int* __restrict__ u,
    const unsigned* __restrict__ cnt_mat,    // exclusive per-bucket scans
    const unsigned* __restrict__ bucket_base,
    unsigned* __restrict__ recs,
    int num_edges, int nb, int nblk) {
    __shared__ unsigned rank[MAX_NB];        // 4 KB: counts -> rank source
    __shared__ unsigned lstart[MAX_NB];      // 4 KB: block-local excl scan
    __shared__ unsigned basesh[MAX_NB];      // 4 KB: global run bases
    __shared__ unsigned srec[B2_CHUNK];      // 16 KB: reordered records
    __shared__ unsigned short sbuk[B2_CHUNK];// 8 KB: bucket per slot
    __shared__ unsigned wtot[4];

    const int tid = threadIdx.x;
    const int blk = blockIdx.x;
    const int estart = blk * B2_CHUNK;
    const int ecount = min(B2_CHUNK, num_edges - estart);

    for (int b = tid; b < MAX_NB; b += 256) rank[b] = 0u;
    for (int b = tid; b < nb; b += 256)
        basesh[b] = bucket_base[b] + cnt_mat[(size_t)b * nblk + blk];
    __syncthreads();

    unsigned rw[B2_EPT];  // packed record (u << 8) | (c & 255)
    int rb[B2_EPT];       // bucket (or -1 invalid)
    unsigned rr[B2_EPT];  // rank within (block, bucket)

    if (ecount == B2_CHUNK) {
        const int4* c4 = (const int4*)(c + estart);
        const int4* u4 = (const int4*)(u + estart);
#pragma unroll
        for (int jj = 0; jj < 4; ++jj) {
            const int k = jj * 256 + tid;
            const int4 cv = c4[k];
            const int4 uv = u4[k];
            const int j = jj * 4;
            rb[j + 0] = cv.x >> NPB_SHIFT;
            rb[j + 1] = cv.y >> NPB_SHIFT;
            rb[j + 2] = cv.z >> NPB_SHIFT;
            rb[j + 3] = cv.w >> NPB_SHIFT;
            rw[j + 0] = ((unsigned)uv.x << NPB_SHIFT) | (unsigned)(cv.x & (NPB - 1));
            rw[j + 1] = ((unsigned)uv.y << NPB_SHIFT) | (unsigned)(cv.y & (NPB - 1));
            rw[j + 2] = ((unsigned)uv.z << NPB_SHIFT) | (unsigned)(cv.z & (NPB - 1));
            rw[j + 3] = ((unsigned)uv.w << NPB_SHIFT) | (unsigned)(cv.w & (NPB - 1));
            rr[j + 0] = atomicAdd(&rank[rb[j + 0]], 1u);
            rr[j + 1] = atomicAdd(&rank[rb[j + 1]], 1u);
            rr[j + 2] = atomicAdd(&rank[rb[j + 2]], 1u);
            rr[j + 3] = atomicAdd(&rank[rb[j + 3]], 1u);
        }
    } else {
#pragma unroll
        for (int j = 0; j < B2_EPT; ++j) {
            rb[j] = -1;
            const int e = estart + j * 256 + tid;
            if (e < num_edges) {
                const int cc = c[e];
                const int uu = u[e];
                rb[j] = cc >> NPB_SHIFT;
                rw[j] = ((unsigned)uu << NPB_SHIFT) | (unsigned)(cc & (NPB - 1));
                rr[j] = atomicAdd(&rank[rb[j]], 1u);
            }
        }
    }
    __syncthreads();

    // block-local exclusive scan of rank[0..MAX_NB) -> lstart
    {
        const int b4 = tid * 4;
        const unsigned v0 = rank[b4 + 0];
        const unsigned v1 = rank[b4 + 1];
        const unsigned v2 = rank[b4 + 2];
        const unsigned v3 = rank[b4 + 3];
        const unsigned tsum = v0 + v1 + v2 + v3;
        unsigned incl = tsum;
        const int lane = tid & 63;
#pragma unroll
        for (int off = 1; off < 64; off <<= 1) {
            const unsigned nv = __shfl_up(incl, off, 64);
            if (lane >= off) incl += nv;
        }
        if (lane == 63) wtot[tid >> 6] = incl;
        __syncthreads();
        unsigned woff = 0;
        const int w = tid >> 6;
        for (int i = 0; i < w; ++i) woff += wtot[i];
        const unsigned ebase = woff + incl - tsum;
        lstart[b4 + 0] = ebase;
        lstart[b4 + 1] = ebase + v0;
        lstart[b4 + 2] = ebase + v0 + v1;
        lstart[b4 + 3] = ebase + v0 + v1 + v2;
    }
    __syncthreads();

    // scatter into LDS in bucket-major order
#pragma unroll
    for (int j = 0; j < B2_EPT; ++j) {
        if (rb[j] >= 0) {
            const unsigned pos = lstart[rb[j]] + rr[j];
            srec[pos] = rw[j];
            sbuk[pos] = (unsigned short)rb[j];
        }
    }
    __syncthreads();

    // coalesced write-out: run-contiguous in both LDS and global
    for (int i = tid; i < ecount; i += 256) {
        const int b = sbuk[i];
        recs[basesh[b] + (unsigned)i - lstart[b]] = srec[i];
    }
}

// Dot-reduce: one block per (bucket, chunk). XCD-pinned swizzle: all CPB
// chunks of a bucket map to the SAME XCD (blockIdx%8 heuristic), so the
// bucket's 16 KB Q tile is an XCD-L2 hit after the first stage. Records
// staged through a 4 KB LDS tile; only the K gather stays random.
__global__ __launch_bounds__(256) void pe_dotred_kernel(
    const unsigned* __restrict__ Qq,
    const unsigned* __restrict__ Kq,
    const unsigned* __restrict__ recs,
    const unsigned* __restrict__ bucket_base,
    float* __restrict__ node_sum,
    int num_nodes, int nb) {
    __shared__ uint4 qlds[NPB * 4];    // 16 KB: row-major, 4 uint4 per row
    __shared__ float acc[NPB];         // 1 KB
    __shared__ unsigned rlds[RT];      // 4 KB record tile

    const int g = blockIdx.x;
    const int xcd = g & (NXCD - 1);
    const int slot = g >> 3;
    const int B = xcd + NXCD * (slot / CPB);
    const int chunk = slot - (slot / CPB) * CPB;
    if (B >= nb) return;

    const int t = threadIdx.x;
    const int gteam = t >> 2;          // team 0..63
    const int sub = t & 3;
    const float inv_scale = 0.125f;    // 1/sqrt(64)

    // stage this bucket's Q rows (contiguous, coalesced)
    const int nrows = min(NPB, num_nodes - B * NPB);
    const uint4* qsrc = (const uint4*)Qq + (size_t)B * NPB * 4;
    for (int i = t; i < nrows * 4; i += 256) qlds[i] = qsrc[i];
    acc[t] = 0.0f;

    const unsigned s0 = bucket_base[B];
    const unsigned len = bucket_base[B + 1] - s0;
    const unsigned r0 = s0 + (unsigned)(((unsigned long long)len * chunk) / CPB);
    const unsigned r1 = s0 + (unsigned)(((unsigned long long)len * (chunk + 1)) / CPB);

    for (unsigned t0 = r0; t0 < r1; t0 += RT) {
        const unsigned n = min((unsigned)RT, r1 - t0);
        __syncthreads();   // also covers initial qlds/acc stores
        for (unsigned i = t; i < n; i += 256) rlds[i] = recs[t0 + i];
        __syncthreads();
        for (unsigned i = gteam; i < n; i += 64) {
            const unsigned rec = rlds[i];            // LDS broadcast per team
            const unsigned uu = rec >> NPB_SHIFT;
            const unsigned local = rec & (NPB - 1);
            const uint4 k = *(const uint4*)(Kq + (size_t)uu * 16 + sub * 4);
            const uint4 q = qlds[local * 4 + sub];   // 2 lanes/bank: free
            const float d = red4(dot16_fp8(q, k));
            if (sub == 0) atomicAdd(&acc[local], __expf(d * inv_scale));
        }
    }
    __syncthreads();

    if (t < nrows && acc[t] != 0.0f)
        atomicAdd(&node_sum[B * NPB + t], acc[t]);
}

// Node pass: lse = log(node_sum[n]) (0 for empty), segment-sum into out.
__global__ __launch_bounds__(256) void pe_node_kernel(
    const float* __restrict__ node_sum,
    const int* __restrict__ batch,
    float* __restrict__ out,
    int num_nodes) {
    const int n = blockIdx.x * blockDim.x + threadIdx.x;
    const bool valid = (n < num_nodes);
    const int nc = valid ? n : (num_nodes - 1);

    const float s = valid ? node_sum[nc] : 0.0f;
    float lse = (s > 0.0f) ? logf(s) : 0.0f;
    if (!valid) lse = 0.0f;
    const int b = batch[nc];

    const int b0 = __shfl(b, 0, 64);
    const bool uniform = __all(b == b0);
    if (uniform) {
        lse += __shfl_xor(lse, 1, 64);
        lse += __shfl_xor(lse, 2, 64);
        lse += __shfl_xor(lse, 4, 64);
        lse += __shfl_xor(lse, 8, 64);
        lse += __shfl_xor(lse, 16, 64);
        lse += __shfl_xor(lse, 32, 64);
        if ((threadIdx.x & 63) == 0 && lse != 0.0f) {
            atomicAdd(&out[b0], lse);
        }
    } else {
        if (valid && lse != 0.0f) {
            atomicAdd(&out[b], lse);
        }
    }
}

// ---------- fallback path (round-0 edge kernel, proven correct) ----------

__global__ __launch_bounds__(256) void pe_edge_kernel(
    const unsigned* __restrict__ Qq,
    const unsigned* __restrict__ Kq,
    const int* __restrict__ c,
    const int* __restrict__ u,
    float* __restrict__ node_sum,
    int num_edges) {
    const int tid = blockIdx.x * blockDim.x + threadIdx.x;
    const int group = tid >> 2;
    const int sub = tid & 3;
    const int ngroups = (gridDim.x * blockDim.x) >> 2;
    const float inv_scale = 0.125f;

    const int E4 = num_edges & ~3;

    for (int base = group * 4; base < E4; base += ngroups * 4) {
        const int4 ci = *(const int4*)(c + base);
        const int4 ui = *(const int4*)(u + base);

        const uint4 q0 = *(const uint4*)(Qq + (size_t)ci.x * 16 + sub * 4);
        const uint4 q1 = *(const uint4*)(Qq + (size_t)ci.y * 16 + sub * 4);
        const uint4 q2 = *(const uint4*)(Qq + (size_t)ci.z * 16 + sub * 4);
        const uint4 q3 = *(const uint4*)(Qq + (size_t)ci.w * 16 + sub * 4);
        const uint4 k0 = *(const uint4*)(Kq + (size_t)ui.x * 16 + sub * 4);
        const uint4 k1 = *(const uint4*)(Kq + (size_t)ui.y * 16 + sub * 4);
        const uint4 k2 = *(const uint4*)(Kq + (size_t)ui.z * 16 + sub * 4);
        const uint4 k3 = *(const uint4*)(Kq + (size_t)ui.w * 16 + sub * 4);

        float d0 = red4(dot16_fp8(q0, k0));
        float d1 = red4(dot16_fp8(q1, k1));
        float d2 = red4(dot16_fp8(q2, k2));
        float d3 = red4(dot16_fp8(q3, k3));

        const float dsel = (sub == 0) ? d0 : (sub == 1) ? d1 : (sub == 2) ? d2 : d3;
        const int csel = (sub == 0) ? ci.x : (sub == 1) ? ci.y : (sub == 2) ? ci.z : ci.w;
        atomicAdd(&node_sum[csel], __expf(dsel * inv_scale));
    }

    for (int e = E4 + group; e < num_edges; e += ngroups) {
        const int cc = c[e];
        const int uu = u[e];
        const uint4 q = *(const uint4*)(Qq + (size_t)cc * 16 + sub * 4);
        const uint4 k = *(const uint4*)(Kq + (size_t)uu * 16 + sub * 4);
        float d = red4(dot16_fp8(q, k));
        if (sub == 0) atomicAdd(&node_sum[cc], __expf(d * inv_scale));
    }
}

extern "C" void kernel_launch(void* const* d_in, const int* in_sizes, int n_in,
                              void* d_out, int out_size, void* d_ws, size_t ws_size,
                              hipStream_t stream) {
    const float* Q2 = (const float*)d_in[0];
    const float* K2 = (const float*)d_in[1];
    const int* c_2 = (const int*)d_in[2];
    const int* u_2 = (const int*)d_in[3];
    const int* batch = (const int*)d_in[4];

    const int num_nodes = in_sizes[4];
    const int num_edges = in_sizes[2];
    const int num_graphs = out_size;
    const int d = in_sizes[0] / num_nodes;   // 64
    const size_t row_elems = (size_t)num_nodes * d;
    const size_t row_bytes = row_elems;      // fp8: 1 B per element

    const int nb = (num_nodes + NPB - 1) >> NPB_SHIFT;
    const int nblk = (num_edges + B2_CHUNK - 1) / B2_CHUNK;

    // ws layout (binned): Qq | Kq | meta (bucket_cnt MAX_NB, bucket_base
    //   MAX_NB+1, pad) | node_sum (ns_pad f32) | recs (E u32) |
    //   cnt_mat (nb*nblk u32)
    // fallback: Qq | Kq | node_sum (at meta)
    unsigned* Qq = (unsigned*)d_ws;
    unsigned* Kq = Qq + row_bytes / 4;
    unsigned* meta = Kq + row_bytes / 4;
    unsigned* bucket_cnt = meta;
    unsigned* bucket_base = meta + MAX_NB;
    float* node_sum_b = (float*)(meta + 2 * MAX_NB + 16);
    const size_t ns_pad = ((size_t)num_nodes + 15) & ~(size_t)15;
    unsigned* recs = (unsigned*)node_sum_b + ns_pad;
    unsigned* cnt_mat = recs + num_edges;
    float* node_sum_f = (float*)meta;        // fallback location
    float* out = (float*)d_out;

    const size_t need_binned = row_bytes * 2 + (size_t)(2 * MAX_NB + 16) * 4 +
                               ns_pad * 4 + (size_t)num_edges * 4 +
                               (size_t)nb * nblk * 4;
    const bool use_binned = (nb <= MAX_NB) && (ws_size >= need_binned) &&
                            (d == 64) && (num_nodes <= (1 << 23));

    float* node_sum = use_binned ? node_sum_b : node_sum_f;

    // Pass 0: fp32 -> fp8 + fused zeroing
    {
        const int n4 = (int)(row_elems / 4);
        const int block = 256;
        const int grid = (n4 + block - 1) / block;
        pe_convert_kernel<<<grid, block, 0, stream>>>(
            Q2, K2, Qq, Kq, node_sum, out, n4, num_nodes, num_graphs);
    }

    if (use_binned) {
        pe_count_kernel<<<nblk, 256, 0, stream>>>(c_2, cnt_mat,
                                                  num_edges, nb, nblk);
        pe_matscan_kernel<<<nb, 256, 0, stream>>>(cnt_mat, bucket_cnt, nblk);
        pe_scan_kernel<<<1, 1024, 0, stream>>>(bucket_cnt, bucket_base, nb);
        pe_binify_kernel<<<nblk, 256, 0, stream>>>(c_2, u_2, cnt_mat,
                                                   bucket_base, recs,
                                                   num_edges, nb, nblk);
        {
            const int grid = NXCD * ((nb + NXCD - 1) / NXCD) * CPB;
            pe_dotred_kernel<<<grid, 256, 0, stream>>>(Qq, Kq, recs,
                                                       bucket_base,
                                                       node_sum, num_nodes, nb);
        }
    } else {
        pe_edge_kernel<<<8192, 256, 0, stream>>>(Qq, Kq, c_2, u_2,
                                                 node_sum, num_edges);
    }

    // Final pass: log + per-graph sum
    {
        const int block = 256;
        const int grid = (num_nodes + block - 1) / block;
        pe_node_kernel<<<grid, block, 0, stream>>>(node_sum, batch, out,
                                                   num_nodes);
    }
}